// Round 7
// baseline (176.499 us; speedup 1.0000x reference)
//
#include <hip/hip_runtime.h>
#include <math.h>

#define N_PTS   10000
#define CIN     64
#define COUT    32
#define KCAP    32
#define RADIUSF 0.07f
#define NCELLS  27
#define QB      4      // queries per block (4 waves; wave w owns query w)
#define MAXC    64     // per-query in-radius cap (Poisson(14.4): P(>64) ~ 1e-26)
#define GRES    14     // hash grid resolution; 1/14 = 0.0714 > R = 0.07
#define GCELLS  (GRES * GRES * GRES)   // 2744
#define APAD    68     // 64 + 4 pad: A-row stride 68 -> <=2-way bank aliasing on MFMA A reads
#define WT_ELEMS (NCELLS * COUT * CIN) // 55296

typedef __attribute__((ext_vector_type(8))) short         bf16x8_t;
typedef __attribute__((ext_vector_type(4))) float         f32x4_t;
typedef __attribute__((ext_vector_type(4))) unsigned int  u32x4;

__device__ __forceinline__ void cell_coords(float x, float y, float z,
                                            int& cx, int& cy, int& cz) {
    cx = (int)(x * (float)GRES); if (cx > GRES - 1) cx = GRES - 1; if (cx < 0) cx = 0;
    cy = (int)(y * (float)GRES); if (cy > GRES - 1) cy = GRES - 1; if (cy < 0) cy = 0;
    cz = (int)(z * (float)GRES); if (cz > GRES - 1) cz = GRES - 1; if (cz < 0) cz = 0;
}

// fp32 -> bf16 with round-to-nearest-even, raw bit arithmetic (finite inputs only;
// bit-identical to __float2bfloat16_rn for non-NaN/Inf)
__device__ __forceinline__ unsigned int f2bf_u(float x) {
    unsigned int u = __float_as_uint(x);
    return (u + 0x7FFFu + ((u >> 16) & 1u)) >> 16;
}
__device__ __forceinline__ unsigned int pack_bf16x2(float lo, float hi) {
    return (f2bf_u(lo) & 0xFFFFu) | (f2bf_u(hi) << 16);
}

// ---- single-block grid build: LDS histogram + scan + scatter, and W -> bf16 Wt ----
__global__ __launch_bounds__(1024) void grid_build_kernel(
    const float* __restrict__ pts,
    const float* __restrict__ W,
    int*   __restrict__ offsets,          // GCELLS+1
    int*   __restrict__ sorted,           // N_PTS
    unsigned short* __restrict__ Wt)      // [cell][o][f] bf16
{
    __shared__ int s_hist[GCELLS];
    __shared__ int s_cur[GCELLS];
    __shared__ int s_scan[1024];
    const int t = threadIdx.x;

    for (int i = t; i < GCELLS; i += 1024) s_hist[i] = 0;
    __syncthreads();

    for (int i = t; i < N_PTS; i += 1024) {
        int cx, cy, cz;
        cell_coords(pts[3 * i], pts[3 * i + 1], pts[3 * i + 2], cx, cy, cz);
        atomicAdd(&s_hist[(cx * GRES + cy) * GRES + cz], 1);
    }
    __syncthreads();

    const int c0 = t * 3;
    int v0 = (c0 + 0 < GCELLS) ? s_hist[c0 + 0] : 0;
    int v1 = (c0 + 1 < GCELLS) ? s_hist[c0 + 1] : 0;
    int v2 = (c0 + 2 < GCELLS) ? s_hist[c0 + 2] : 0;
    s_scan[t] = v0 + v1 + v2;
    __syncthreads();
    for (int d = 1; d < 1024; d <<= 1) {          // inclusive Hillis-Steele
        int add = (t >= d) ? s_scan[t - d] : 0;
        __syncthreads();
        s_scan[t] += add;
        __syncthreads();
    }
    int base = (t == 0) ? 0 : s_scan[t - 1];
    if (c0 + 0 < GCELLS) { offsets[c0 + 0] = base; s_cur[c0 + 0] = base; base += v0; }
    if (c0 + 1 < GCELLS) { offsets[c0 + 1] = base; s_cur[c0 + 1] = base; base += v1; }
    if (c0 + 2 < GCELLS) { offsets[c0 + 2] = base; s_cur[c0 + 2] = base; base += v2; }
    if (t == 1023) offsets[GCELLS] = s_scan[1023];
    __syncthreads();

    for (int i = t; i < N_PTS; i += 1024) {
        int cx, cy, cz;
        cell_coords(pts[3 * i], pts[3 * i + 1], pts[3 * i + 2], cx, cy, cz);
        int pos = atomicAdd(&s_cur[(cx * GRES + cy) * GRES + cz], 1);
        sorted[pos] = i;
    }

    // W[cell][f][o] f32 -> Wt[cell][o][f] bf16 (coalesced writes)
    for (int idx = t; idx < WT_ELEMS; idx += 1024) {
        int f    = idx & (CIN - 1);
        int o    = (idx >> 6) & (COUT - 1);
        int cell = idx >> 11;
        Wt[idx] = (unsigned short)f2bf_u(W[(cell * CIN + f) * COUT + o]);
    }
}

// ---- main fused kernel: grid radius search + trilinear scatter + MFMA contraction ----
__global__ __launch_bounds__(256) void cconv_grid_mfma_kernel(
    const float* __restrict__ feats,
    const float* __restrict__ points,
    const unsigned short* __restrict__ Wt,   // [27][32][64] bf16
    const float* __restrict__ bias,
    const int*   __restrict__ offsets,
    const int*   __restrict__ sorted,
    float* __restrict__ out)
{
    const int tid  = threadIdx.x;
    const int lane = tid & 63;
    const int wave = tid >> 6;

    __shared__ __align__(16) float sA[QB][NCELLS][APAD];
    __shared__ float sC[QB][QB][COUT];        // [wave][q][o] partials
    __shared__ float s_d2[QB][MAXC];
    __shared__ int   s_idx[QB][MAXC];
    __shared__ int   s_sel[QB][KCAP];
    __shared__ int   s_cnt[QB];
    __shared__ int   s_qi[QB];
    __shared__ int   s_nn[QB];

    if (lane == 0) s_cnt[wave] = 0;
    for (int i = lane; i < NCELLS * APAD; i += 64) ((float*)sA[wave])[i] = 0.0f;

    const int q_flat = blockIdx.x * QB + wave;
    const int qi = sorted[q_flat];
    const float qx = points[3 * qi + 0];
    const float qy = points[3 * qi + 1];
    const float qz = points[3 * qi + 2];
    const float sqn = qx * qx + qy * qy + qz * qz;
    const float r2 = RADIUSF * RADIUSF;

    int cx, cy, cz;
    cell_coords(qx, qy, qz, cx, cy, cz);

    // ---- Phase 1: candidate scan over neighbor cells (9 contiguous z-rows) ----
    for (int dx = -1; dx <= 1; ++dx) {
        int cxx = cx + dx;
        if (cxx < 0 || cxx > GRES - 1) continue;
        for (int dy = -1; dy <= 1; ++dy) {
            int cyy = cy + dy;
            if (cyy < 0 || cyy > GRES - 1) continue;
            int zlo = cz - 1; if (zlo < 0) zlo = 0;
            int zhi = cz + 1; if (zhi > GRES - 1) zhi = GRES - 1;
            int row = (cxx * GRES + cyy) * GRES;
            int s = offsets[row + zlo];
            int e = offsets[row + zhi + 1];
            for (int base = s; base < e; base += 64) {
                int t = base + lane;
                if (t < e) {
                    int j = sorted[t];
                    float x = points[3 * j + 0];
                    float y = points[3 * j + 1];
                    float z = points[3 * j + 2];
                    float sqj = x * x + y * y + z * z;
                    float dot = qx * x + qy * y + qz * z;
                    float d2 = (sqn + sqj) - 2.0f * dot;   // byte-identical to ref form
                    if (d2 <= r2) {
                        int pos = atomicAdd(&s_cnt[wave], 1);
                        if (pos < MAXC) { s_d2[wave][pos] = d2; s_idx[wave][pos] = j; }
                    }
                }
            }
        }
    }

    int M = s_cnt[wave]; if (M > MAXC) M = MAXC;
    const int cnt = (M > KCAP) ? KCAP : M;

    if (M > KCAP) {   // exact top-32, tie-break matches lax.top_k (d2, then index)
        if (lane < M) {
            float dc = s_d2[wave][lane];
            int   ic = s_idx[wave][lane];
            int rank = 0;
            for (int m = 0; m < M; ++m) {
                float dm = s_d2[wave][m];
                int   im = s_idx[wave][m];
                rank += (dm < dc || (dm == dc && im < ic)) ? 1 : 0;
            }
            if (rank < KCAP) s_sel[wave][rank] = s_idx[wave][lane];
        }
    }
    const int* nbr = (M > KCAP) ? s_sel[wave] : s_idx[wave];
    if (lane == 0) { s_qi[wave] = qi; s_nn[wave] = cnt; }

    // ---- Phase 2: trilinear scatter-accumulate (lane = feature) ----
    for (int k = 0; k < cnt; ++k) {
        int j = nbr[k];
        float x = points[3 * j + 0];
        float y = points[3 * j + 1];
        float z = points[3 * j + 2];
        float rx = (x - qx) / RADIUSF;
        float ry = (y - qy) / RADIUSF;
        float rz = (z - qz) / RADIUSF;
        float l2 = sqrtf(rx * rx + ry * ry + rz * rz);
        float ax = fabsf(rx), ay = fabsf(ry), az = fabsf(rz);
        float linf = fmaxf(fmaxf(ax, ay), az);
        float s = (linf > 0.0f) ? (l2 / fmaxf(linf, 1e-12f)) : 0.0f;
        float tx = rx * s, ty = ry * s, tz = rz * s;
        float cxf = (tx + 1.0f) * 0.5f * 2.0f;
        float cyf = (ty + 1.0f) * 0.5f * 2.0f;
        float czf = (tz + 1.0f) * 0.5f * 2.0f;
        float c0x = fminf(fmaxf(floorf(cxf), 0.0f), 1.0f);
        float c0y = fminf(fmaxf(floorf(cyf), 0.0f), 1.0f);
        float c0z = fminf(fmaxf(floorf(czf), 0.0f), 1.0f);
        float fx = cxf - c0x;
        float fy = cyf - c0y;
        float fz = czf - c0z;
        int i0 = (int)c0x, i1 = (int)c0y, i2 = (int)c0z;
        int base = i0 * 9 + i1 * 3 + i2;

        float gx0 = 1.0f - fx, gx1 = fx;
        float gy0 = 1.0f - fy, gy1 = fy;
        float gz0 = 1.0f - fz, gz1 = fz;

        float featv = feats[j * CIN + lane];

        sA[wave][base + 0 ][lane] += (gx0 * gy0) * gz0 * featv;
        sA[wave][base + 1 ][lane] += (gx0 * gy0) * gz1 * featv;
        sA[wave][base + 3 ][lane] += (gx0 * gy1) * gz0 * featv;
        sA[wave][base + 4 ][lane] += (gx0 * gy1) * gz1 * featv;
        sA[wave][base + 9 ][lane] += (gx1 * gy0) * gz0 * featv;
        sA[wave][base + 10][lane] += (gx1 * gy0) * gz1 * featv;
        sA[wave][base + 12][lane] += (gx1 * gy1) * gz0 * featv;
        sA[wave][base + 13][lane] += (gx1 * gy1) * gz1 * featv;
    }
    __syncthreads();   // all waves' sA / s_qi / s_nn now visible

    // ---- Phase 3: MFMA contraction  out[4x32] = A[4x1728] * W[1728x32] ----
    // mfma_f32_16x16x32_bf16: A lane map (row=lane&15, k=8*(lane>>4)+j),
    // B lane map (col=lane&15, k=8*(lane>>4)+j), C map (col=lane&15, row=4*(lane>>4)+reg).
    // Rows 0..3 = this block's queries; rows 4..15 zero-padded.
    f32x4_t acc0 = {0.f, 0.f, 0.f, 0.f};
    f32x4_t acc1 = {0.f, 0.f, 0.f, 0.f};
    const int r  = lane & 15;
    const int kg = lane >> 4;
    for (int s = wave; s < 2 * NCELLS; s += QB) {   // 54 K-steps, round-robin
        const int c  = s >> 1;
        const int f0 = (s & 1) << 5;
        bf16x8_t af = {};
        if (r < QB) {
            const float* Ap = &sA[r][c][f0 + kg * 8];
            u32x4 au;
            #pragma unroll
            for (int p = 0; p < 4; ++p) {
                au[p] = pack_bf16x2(Ap[2 * p], Ap[2 * p + 1]);
            }
            af = __builtin_bit_cast(bf16x8_t, au);
        }
        const unsigned short* wp0 = Wt + ((c * COUT + r     ) * CIN + f0 + kg * 8);
        const unsigned short* wp1 = Wt + ((c * COUT + 16 + r) * CIN + f0 + kg * 8);
        bf16x8_t bf0 = *(const bf16x8_t*)wp0;
        bf16x8_t bf1 = *(const bf16x8_t*)wp1;
        acc0 = __builtin_amdgcn_mfma_f32_16x16x32_bf16(af, bf0, acc0, 0, 0, 0);
        acc1 = __builtin_amdgcn_mfma_f32_16x16x32_bf16(af, bf1, acc1, 0, 0, 0);
    }
    if (lane < 16) {
        #pragma unroll
        for (int j = 0; j < QB; ++j) {        // j = query row
            sC[wave][j][lane]      = acc0[j];
            sC[wave][j][16 + lane] = acc1[j];
        }
    }
    __syncthreads();

    if (tid < QB * COUT) {
        int q = tid >> 5, o = tid & 31;
        float v = sC[0][q][o] + sC[1][q][o] + sC[2][q][o] + sC[3][q][o];
        float nn = (float)s_nn[q];
        out[s_qi[q] * COUT + o] = v / fmaxf(nn, 1.0f) + bias[o];
    }
}

// ---- fallback (validated Round-3 kernel) if workspace is too small ----
__global__ __launch_bounds__(64) void cconv_fused_kernel(
    const float* __restrict__ feats,
    const float* __restrict__ points,
    const float* __restrict__ W,
    const float* __restrict__ bias,
    float* __restrict__ out)
{
    const int n    = blockIdx.x;
    const int lane = threadIdx.x;

    __shared__ float sA[NCELLS][CIN];
    __shared__ float s_d2[128];
    __shared__ int   s_idx[128];
    __shared__ int   s_rank[128];
    __shared__ int   s_sel[KCAP];
    __shared__ int   s_cnt;

    if (lane == 0) s_cnt = 0;
    for (int c = lane; c < NCELLS * CIN; c += 64) ((float*)sA)[c] = 0.0f;
    __syncthreads();

    const float qx = points[3 * n + 0];
    const float qy = points[3 * n + 1];
    const float qz = points[3 * n + 2];
    const float sqn = qx * qx + qy * qy + qz * qz;
    const float r2 = RADIUSF * RADIUSF;

    for (int j = lane; j < N_PTS; j += 64) {
        float x = points[3 * j + 0];
        float y = points[3 * j + 1];
        float z = points[3 * j + 2];
        float sqj = x * x + y * y + z * z;
        float dot = qx * x + qy * y + qz * z;
        float d2 = (sqn + sqj) - 2.0f * dot;
        if (d2 <= r2) {
            int pos = atomicAdd(&s_cnt, 1);
            if (pos < 128) { s_d2[pos] = d2; s_idx[pos] = j; }
        }
    }
    __syncthreads();

    int M = s_cnt; if (M > 128) M = 128;
    int cnt;
    if (M > KCAP) {
        for (int c = lane; c < M; c += 64) {
            float dc = s_d2[c]; int ic = s_idx[c]; int rank = 0;
            for (int m = 0; m < M; ++m) {
                float dm = s_d2[m]; int im = s_idx[m];
                rank += (dm < dc || (dm == dc && im < ic)) ? 1 : 0;
            }
            s_rank[c] = rank;
        }
        __syncthreads();
        for (int c = lane; c < M; c += 64) {
            int r = s_rank[c];
            if (r < KCAP) s_sel[r] = s_idx[c];
        }
        __syncthreads();
        cnt = KCAP;
    } else cnt = M;
    const int* nbr = (M > KCAP) ? s_sel : s_idx;

    for (int k = 0; k < cnt; ++k) {
        int j = nbr[k];
        float x = points[3 * j + 0];
        float y = points[3 * j + 1];
        float z = points[3 * j + 2];
        float rx = (x - qx) / RADIUSF;
        float ry = (y - qy) / RADIUSF;
        float rz = (z - qz) / RADIUSF;
        float l2 = sqrtf(rx * rx + ry * ry + rz * rz);
        float ax = fabsf(rx), ay = fabsf(ry), az = fabsf(rz);
        float linf = fmaxf(fmaxf(ax, ay), az);
        float s = (linf > 0.0f) ? (l2 / fmaxf(linf, 1e-12f)) : 0.0f;
        float tx = rx * s, ty = ry * s, tz = rz * s;
        float cxf = (tx + 1.0f) * 0.5f * 2.0f;
        float cyf = (ty + 1.0f) * 0.5f * 2.0f;
        float czf = (tz + 1.0f) * 0.5f * 2.0f;
        float c0x = fminf(fmaxf(floorf(cxf), 0.0f), 1.0f);
        float c0y = fminf(fmaxf(floorf(cyf), 0.0f), 1.0f);
        float c0z = fminf(fmaxf(floorf(czf), 0.0f), 1.0f);
        float fx = cxf - c0x, fy = cyf - c0y, fz = czf - c0z;
        int i0 = (int)c0x, i1 = (int)c0y, i2 = (int)c0z;
        int base = i0 * 9 + i1 * 3 + i2;
        float gx0 = 1.0f - fx, gx1 = fx;
        float gy0 = 1.0f - fy, gy1 = fy;
        float gz0 = 1.0f - fz, gz1 = fz;
        float featv = feats[j * CIN + lane];
        sA[base + 0 ][lane] += (gx0 * gy0) * gz0 * featv;
        sA[base + 1 ][lane] += (gx0 * gy0) * gz1 * featv;
        sA[base + 3 ][lane] += (gx0 * gy1) * gz0 * featv;
        sA[base + 4 ][lane] += (gx0 * gy1) * gz1 * featv;
        sA[base + 9 ][lane] += (gx1 * gy0) * gz0 * featv;
        sA[base + 10][lane] += (gx1 * gy0) * gz1 * featv;
        sA[base + 12][lane] += (gx1 * gy1) * gz0 * featv;
        sA[base + 13][lane] += (gx1 * gy1) * gz1 * featv;
    }
    __syncthreads();

    const int o    = lane & 31;
    const int half = lane >> 5;
    const int c_begin = half ? 14 : 0;
    const int c_end   = half ? 27 : 14;
    float acc = 0.0f;
    for (int cell = c_begin; cell < c_end; ++cell) {
        const float* __restrict__ Wrow = W + (cell * CIN) * COUT + o;
        #pragma unroll 8
        for (int f = 0; f < CIN; ++f) acc += sA[cell][f] * Wrow[f * COUT];
    }
    acc += __shfl_xor(acc, 32);
    if (lane < COUT) {
        float nn = (float)cnt;
        out[n * COUT + lane] = acc / fmaxf(nn, 1.0f) + bias[lane];
    }
}

extern "C" void kernel_launch(void* const* d_in, const int* in_sizes, int n_in,
                              void* d_out, int out_size, void* d_ws, size_t ws_size,
                              hipStream_t stream) {
    const float* feats  = (const float*)d_in[0];
    const float* points = (const float*)d_in[1];
    const float* W      = (const float*)d_in[2];
    const float* bias   = (const float*)d_in[3];
    float* out = (float*)d_out;

    // workspace layout: Wt (bf16, 16B-aligned at base) | offsets | sorted
    const size_t wt_bytes  = (size_t)WT_ELEMS * sizeof(unsigned short); // 110592
    const size_t need = wt_bytes + (size_t)(GCELLS + 1 + N_PTS) * sizeof(int);

    if (ws_size >= need) {
        unsigned short* Wt = (unsigned short*)d_ws;
        int* offsets = (int*)((char*)d_ws + wt_bytes);   // GCELLS+1
        int* sorted  = offsets + GCELLS + 1;             // N_PTS

        grid_build_kernel<<<1, 1024, 0, stream>>>(points, W, offsets, sorted, Wt);
        cconv_grid_mfma_kernel<<<N_PTS / QB, QB * 64, 0, stream>>>(
            feats, points, Wt, bias, offsets, sorted, out);
    } else {
        cconv_fused_kernel<<<N_PTS, 64, 0, stream>>>(feats, points, W, bias, out);
    }
}

// Round 8
// 141.419 us; speedup vs baseline: 1.2481x; 1.2481x over previous
//
#include <hip/hip_runtime.h>
#include <math.h>

#define N_PTS   10000
#define CIN     64
#define COUT    32
#define KCAP    32
#define RADIUSF 0.07f
#define NCELLS  27
#define QB      4      // queries per block (4 waves; wave w owns query w)
#define MAXC    64     // per-query in-radius cap (Poisson(14.4): P(>64) ~ 1e-26)
#define GRES    14     // hash grid resolution; 1/14 = 0.0714 > R = 0.07
#define GCELLS  (GRES * GRES * GRES)   // 2744
#define APAD    68     // sA row stride (floats)
#define WT_ELEMS (NCELLS * COUT * CIN) // 55296

typedef __attribute__((ext_vector_type(8))) short         bf16x8_t;
typedef __attribute__((ext_vector_type(4))) float         f32x4_t;
typedef __attribute__((ext_vector_type(4))) unsigned int  u32x4;

__device__ __forceinline__ void cell_coords(float x, float y, float z,
                                            int& cx, int& cy, int& cz) {
    cx = (int)(x * (float)GRES); if (cx > GRES - 1) cx = GRES - 1; if (cx < 0) cx = 0;
    cy = (int)(y * (float)GRES); if (cy > GRES - 1) cy = GRES - 1; if (cy < 0) cy = 0;
    cz = (int)(z * (float)GRES); if (cz > GRES - 1) cz = GRES - 1; if (cz < 0) cz = 0;
}

// fp32 -> bf16 round-to-nearest-even, raw bits (finite inputs)
__device__ __forceinline__ unsigned int f2bf_u(float x) {
    unsigned int u = __float_as_uint(x);
    return (u + 0x7FFFu + ((u >> 16) & 1u)) >> 16;
}
__device__ __forceinline__ unsigned int pack_bf16x2(float lo, float hi) {
    return (f2bf_u(lo) & 0xFFFFu) | (f2bf_u(hi) << 16);
}

// ---- build k1: per-cell histogram (parallel) ----
__global__ void grid_count_kernel(const float* __restrict__ pts, int* __restrict__ counts) {
    int i = blockIdx.x * 256 + threadIdx.x;
    if (i >= N_PTS) return;
    int cx, cy, cz;
    cell_coords(pts[3 * i], pts[3 * i + 1], pts[3 * i + 2], cx, cy, cz);
    atomicAdd(&counts[(cx * GRES + cy) * GRES + cz], 1);
}

// ---- build k2: exclusive scan over 2744 cells (single small block job) ----
__global__ __launch_bounds__(1024) void grid_scan_kernel(const int* __restrict__ counts,
                                                         int* __restrict__ offsets,
                                                         int* __restrict__ cursor) {
    __shared__ int s[1024];
    const int t = threadIdx.x;
    const int c0 = t * 3;
    int v0 = 0, v1 = 0, v2 = 0, sum = 0;
    if (c0 + 0 < GCELLS) { v0 = counts[c0 + 0]; sum += v0; }
    if (c0 + 1 < GCELLS) { v1 = counts[c0 + 1]; sum += v1; }
    if (c0 + 2 < GCELLS) { v2 = counts[c0 + 2]; sum += v2; }
    s[t] = sum;
    __syncthreads();
    for (int d = 1; d < 1024; d <<= 1) {           // inclusive Hillis-Steele
        int add = (t >= d) ? s[t - d] : 0;
        __syncthreads();
        s[t] += add;
        __syncthreads();
    }
    int base = (t == 0) ? 0 : s[t - 1];
    if (c0 + 0 < GCELLS) { offsets[c0 + 0] = base; cursor[c0 + 0] = base; base += v0; }
    if (c0 + 1 < GCELLS) { offsets[c0 + 1] = base; cursor[c0 + 1] = base; base += v1; }
    if (c0 + 2 < GCELLS) { offsets[c0 + 2] = base; cursor[c0 + 2] = base; base += v2; }
    if (t == 1023) offsets[GCELLS] = s[1023];
}

// ---- build k3: scatter indices AND cell-sorted point copies (parallel) ----
__global__ void grid_scatter_kernel(const float* __restrict__ pts,
                                    int* __restrict__ cursor,
                                    int* __restrict__ sorted,
                                    float* __restrict__ pts_s) {
    int i = blockIdx.x * 256 + threadIdx.x;
    if (i >= N_PTS) return;
    float x = pts[3 * i + 0], y = pts[3 * i + 1], z = pts[3 * i + 2];
    int cx, cy, cz;
    cell_coords(x, y, z, cx, cy, cz);
    int pos = atomicAdd(&cursor[(cx * GRES + cy) * GRES + cz], 1);
    sorted[pos] = i;
    pts_s[3 * pos + 0] = x;   // bitwise copies -> d2 stays byte-identical
    pts_s[3 * pos + 1] = y;
    pts_s[3 * pos + 2] = z;
}

// ---- build k4: W[cell][f][o] f32 -> Wt[cell][o][f] bf16, LDS transpose (parallel) ----
__global__ __launch_bounds__(256) void wt_transpose_kernel(const float* __restrict__ W,
                                                           unsigned short* __restrict__ Wt) {
    __shared__ float tile[CIN * 33];   // [f][o] padded: bank = (f+o)%32 on transposed read
    const int cell = blockIdx.x;
    const int t = threadIdx.x;
    for (int idx = t; idx < CIN * COUT; idx += 256) {
        int f = idx >> 5, o = idx & 31;
        tile[f * 33 + o] = W[cell * (CIN * COUT) + idx];    // coalesced read
    }
    __syncthreads();
    for (int idx = t; idx < CIN * COUT; idx += 256) {
        int o = idx >> 6, f = idx & 63;
        Wt[cell * (CIN * COUT) + idx] = (unsigned short)f2bf_u(tile[f * 33 + o]);
    }
}

// ---- main fused kernel ----
__global__ __launch_bounds__(256) void cconv_grid_mfma_kernel(
    const float* __restrict__ feats,
    const unsigned short* __restrict__ Wt,   // [27][32][64] bf16
    const float* __restrict__ bias,
    const int*   __restrict__ offsets,
    const int*   __restrict__ sorted,
    const float* __restrict__ pts_s,         // cell-sorted point copies
    float* __restrict__ out)
{
    const int tid  = threadIdx.x;
    const int lane = tid & 63;
    const int wave = tid >> 6;

    __shared__ __align__(16) float sA[QB][NCELLS][APAD];
    __shared__ float sC[QB][QB][COUT];
    __shared__ float s_d2[QB][MAXC];
    __shared__ float s_px[QB][MAXC];
    __shared__ float s_py[QB][MAXC];
    __shared__ float s_pz[QB][MAXC];
    __shared__ int   s_idx[QB][MAXC];
    __shared__ int   s_sel[QB][KCAP];
    __shared__ int   s_cnt[QB];
    __shared__ int   s_qi[QB];
    __shared__ int   s_nn[QB];

    if (lane == 0) s_cnt[wave] = 0;

    const int q_flat = blockIdx.x * QB + wave;
    const int qi = sorted[q_flat];
    const float qx = pts_s[3 * q_flat + 0];   // == points[qi], bitwise
    const float qy = pts_s[3 * q_flat + 1];
    const float qz = pts_s[3 * q_flat + 2];
    const float sqn = qx * qx + qy * qy + qz * qz;
    const float r2 = RADIUSF * RADIUSF;

    int cx, cy, cz;
    cell_coords(qx, qy, qz, cx, cy, cz);

    // ---- Phase 1: candidate scan, coalesced pts_s reads; stash accepted coords ----
    for (int dx = -1; dx <= 1; ++dx) {
        int cxx = cx + dx;
        if (cxx < 0 || cxx > GRES - 1) continue;
        for (int dy = -1; dy <= 1; ++dy) {
            int cyy = cy + dy;
            if (cyy < 0 || cyy > GRES - 1) continue;
            int zlo = cz - 1; if (zlo < 0) zlo = 0;
            int zhi = cz + 1; if (zhi > GRES - 1) zhi = GRES - 1;
            int row = (cxx * GRES + cyy) * GRES;
            int s = offsets[row + zlo];
            int e = offsets[row + zhi + 1];
            for (int base = s; base < e; base += 64) {
                int t = base + lane;
                if (t < e) {
                    float x = pts_s[3 * t + 0];
                    float y = pts_s[3 * t + 1];
                    float z = pts_s[3 * t + 2];
                    float sqj = x * x + y * y + z * z;
                    float dot = qx * x + qy * y + qz * z;
                    float d2 = (sqn + sqj) - 2.0f * dot;   // byte-identical to ref form
                    if (d2 <= r2) {
                        int pos = atomicAdd(&s_cnt[wave], 1);
                        if (pos < MAXC) {
                            s_d2[wave][pos] = d2;
                            s_idx[wave][pos] = sorted[t];
                            s_px[wave][pos] = x;
                            s_py[wave][pos] = y;
                            s_pz[wave][pos] = z;
                        }
                    }
                }
            }
        }
    }

    int M = s_cnt[wave]; if (M > MAXC) M = MAXC;
    const int cnt = (M > KCAP) ? KCAP : M;
    const bool over = (M > KCAP);

    if (over) {   // exact top-32; tie-break matches lax.top_k (d2, then original index)
        if (lane < M) {
            float dc = s_d2[wave][lane];
            int   ic = s_idx[wave][lane];
            int rank = 0;
            for (int m = 0; m < M; ++m) {
                float dm = s_d2[wave][m];
                int   im = s_idx[wave][m];
                rank += (dm < dc || (dm == dc && im < ic)) ? 1 : 0;
            }
            if (rank < KCAP) s_sel[wave][rank] = lane;   // store SLOT
        }
    }
    if (lane == 0) { s_qi[wave] = qi; s_nn[wave] = cnt; }

    // ---- Phase 2: register-accumulated trilinear scatter (lane = feature) ----
    float a[NCELLS];
    #pragma unroll
    for (int c = 0; c < NCELLS; ++c) a[c] = 0.0f;

    for (int k = 0; k < cnt; ++k) {
        int slot = over ? s_sel[wave][k] : k;
        int j = s_idx[wave][slot];
        float x = s_px[wave][slot];   // broadcast LDS reads
        float y = s_py[wave][slot];
        float z = s_pz[wave][slot];
        float rx = (x - qx) / RADIUSF;
        float ry = (y - qy) / RADIUSF;
        float rz = (z - qz) / RADIUSF;
        float l2 = sqrtf(rx * rx + ry * ry + rz * rz);
        float ax = fabsf(rx), ay = fabsf(ry), az = fabsf(rz);
        float linf = fmaxf(fmaxf(ax, ay), az);
        float s = (linf > 0.0f) ? (l2 / fmaxf(linf, 1e-12f)) : 0.0f;
        float tx = rx * s, ty = ry * s, tz = rz * s;
        float cxf = (tx + 1.0f) * 0.5f * 2.0f;
        float cyf = (ty + 1.0f) * 0.5f * 2.0f;
        float czf = (tz + 1.0f) * 0.5f * 2.0f;
        float c0x = fminf(fmaxf(floorf(cxf), 0.0f), 1.0f);
        float c0y = fminf(fmaxf(floorf(cyf), 0.0f), 1.0f);
        float c0z = fminf(fmaxf(floorf(czf), 0.0f), 1.0f);
        float fx = cxf - c0x;
        float fy = cyf - c0y;
        float fz = czf - c0z;
        int i0 = (int)c0x, i1 = (int)c0y, i2 = (int)c0z;

        float gx0 = 1.0f - fx, gx1 = fx;
        float gy0 = 1.0f - fy, gy1 = fy;
        float gz0 = 1.0f - fz, gz1 = fz;

        // per-axis weights over the 3 kernel planes (zeros where untouched)
        float wx0 = i0 ? 0.0f : gx0, wx1 = i0 ? gx0 : gx1, wx2 = i0 ? gx1 : 0.0f;
        float wy0 = i1 ? 0.0f : gy0, wy1 = i1 ? gy0 : gy1, wy2 = i1 ? gy1 : 0.0f;
        float wz0 = i2 ? 0.0f : gz0, wz1 = i2 ? gz0 : gz1, wz2 = i2 ? gz1 : 0.0f;

        float featv = feats[j * CIN + lane];   // coalesced
        float pz0 = wz0 * featv, pz1 = wz1 * featv, pz2 = wz2 * featv;
        float wxv[3] = {wx0, wx1, wx2};
        float wyv[3] = {wy0, wy1, wy2};
        float pzv[3] = {pz0, pz1, pz2};

        #pragma unroll
        for (int ci = 0; ci < 3; ++ci) {
            #pragma unroll
            for (int cj = 0; cj < 3; ++cj) {
                float wxy = wxv[ci] * wyv[cj];
                #pragma unroll
                for (int ck = 0; ck < 3; ++ck) {
                    a[ci * 9 + cj * 3 + ck] = fmaf(wxy, pzv[ck], a[ci * 9 + cj * 3 + ck]);
                }
            }
        }
    }
    #pragma unroll
    for (int c = 0; c < NCELLS; ++c) sA[wave][c][lane] = a[c];   // conflict-free
    __syncthreads();

    // ---- Phase 3: MFMA contraction  out[4x32] = A[4x1728] * W[1728x32] ----
    f32x4_t acc0 = {0.f, 0.f, 0.f, 0.f};
    f32x4_t acc1 = {0.f, 0.f, 0.f, 0.f};
    const int r  = lane & 15;
    const int kg = lane >> 4;
    for (int s = wave; s < 2 * NCELLS; s += QB) {   // 54 K-steps, round-robin
        const int c  = s >> 1;
        const int f0 = (s & 1) << 5;
        bf16x8_t af = {};
        if (r < QB) {
            const float* Ap = &sA[r][c][f0 + kg * 8];
            u32x4 au;
            #pragma unroll
            for (int p = 0; p < 4; ++p) au[p] = pack_bf16x2(Ap[2 * p], Ap[2 * p + 1]);
            af = __builtin_bit_cast(bf16x8_t, au);
        }
        const unsigned short* wp0 = Wt + ((c * COUT + r     ) * CIN + f0 + kg * 8);
        const unsigned short* wp1 = Wt + ((c * COUT + 16 + r) * CIN + f0 + kg * 8);
        bf16x8_t bf0 = *(const bf16x8_t*)wp0;
        bf16x8_t bf1 = *(const bf16x8_t*)wp1;
        acc0 = __builtin_amdgcn_mfma_f32_16x16x32_bf16(af, bf0, acc0, 0, 0, 0);
        acc1 = __builtin_amdgcn_mfma_f32_16x16x32_bf16(af, bf1, acc1, 0, 0, 0);
    }
    if (lane < 16) {
        #pragma unroll
        for (int j = 0; j < QB; ++j) {
            sC[wave][j][lane]      = acc0[j];
            sC[wave][j][16 + lane] = acc1[j];
        }
    }
    __syncthreads();

    if (tid < QB * COUT) {
        int q = tid >> 5, o = tid & 31;
        float v = sC[0][q][o] + sC[1][q][o] + sC[2][q][o] + sC[3][q][o];
        float nn = (float)s_nn[q];
        out[s_qi[q] * COUT + o] = v / fmaxf(nn, 1.0f) + bias[o];
    }
}

// ---- fallback (validated Round-3 kernel) if workspace is too small ----
__global__ __launch_bounds__(64) void cconv_fused_kernel(
    const float* __restrict__ feats,
    const float* __restrict__ points,
    const float* __restrict__ W,
    const float* __restrict__ bias,
    float* __restrict__ out)
{
    const int n    = blockIdx.x;
    const int lane = threadIdx.x;

    __shared__ float sA[NCELLS][CIN];
    __shared__ float s_d2[128];
    __shared__ int   s_idx[128];
    __shared__ int   s_rank[128];
    __shared__ int   s_sel[KCAP];
    __shared__ int   s_cnt;

    if (lane == 0) s_cnt = 0;
    for (int c = lane; c < NCELLS * CIN; c += 64) ((float*)sA)[c] = 0.0f;
    __syncthreads();

    const float qx = points[3 * n + 0];
    const float qy = points[3 * n + 1];
    const float qz = points[3 * n + 2];
    const float sqn = qx * qx + qy * qy + qz * qz;
    const float r2 = RADIUSF * RADIUSF;

    for (int j = lane; j < N_PTS; j += 64) {
        float x = points[3 * j + 0];
        float y = points[3 * j + 1];
        float z = points[3 * j + 2];
        float sqj = x * x + y * y + z * z;
        float dot = qx * x + qy * y + qz * z;
        float d2 = (sqn + sqj) - 2.0f * dot;
        if (d2 <= r2) {
            int pos = atomicAdd(&s_cnt, 1);
            if (pos < 128) { s_d2[pos] = d2; s_idx[pos] = j; }
        }
    }
    __syncthreads();

    int M = s_cnt; if (M > 128) M = 128;
    int cnt;
    if (M > KCAP) {
        for (int c = lane; c < M; c += 64) {
            float dc = s_d2[c]; int ic = s_idx[c]; int rank = 0;
            for (int m = 0; m < M; ++m) {
                float dm = s_d2[m]; int im = s_idx[m];
                rank += (dm < dc || (dm == dc && im < ic)) ? 1 : 0;
            }
            s_rank[c] = rank;
        }
        __syncthreads();
        for (int c = lane; c < M; c += 64) {
            int r = s_rank[c];
            if (r < KCAP) s_sel[r] = s_idx[c];
        }
        __syncthreads();
        cnt = KCAP;
    } else cnt = M;
    const int* nbr = (M > KCAP) ? s_sel : s_idx;

    for (int k = 0; k < cnt; ++k) {
        int j = nbr[k];
        float x = points[3 * j + 0];
        float y = points[3 * j + 1];
        float z = points[3 * j + 2];
        float rx = (x - qx) / RADIUSF;
        float ry = (y - qy) / RADIUSF;
        float rz = (z - qz) / RADIUSF;
        float l2 = sqrtf(rx * rx + ry * ry + rz * rz);
        float ax = fabsf(rx), ay = fabsf(ry), az = fabsf(rz);
        float linf = fmaxf(fmaxf(ax, ay), az);
        float s = (linf > 0.0f) ? (l2 / fmaxf(linf, 1e-12f)) : 0.0f;
        float tx = rx * s, ty = ry * s, tz = rz * s;
        float cxf = (tx + 1.0f) * 0.5f * 2.0f;
        float cyf = (ty + 1.0f) * 0.5f * 2.0f;
        float czf = (tz + 1.0f) * 0.5f * 2.0f;
        float c0x = fminf(fmaxf(floorf(cxf), 0.0f), 1.0f);
        float c0y = fminf(fmaxf(floorf(cyf), 0.0f), 1.0f);
        float c0z = fminf(fmaxf(floorf(czf), 0.0f), 1.0f);
        float fx = cxf - c0x, fy = cyf - c0y, fz = czf - c0z;
        int i0 = (int)c0x, i1 = (int)c0y, i2 = (int)c0z;
        int base = i0 * 9 + i1 * 3 + i2;
        float gx0 = 1.0f - fx, gx1 = fx;
        float gy0 = 1.0f - fy, gy1 = fy;
        float gz0 = 1.0f - fz, gz1 = fz;
        float featv = feats[j * CIN + lane];
        sA[base + 0 ][lane] += (gx0 * gy0) * gz0 * featv;
        sA[base + 1 ][lane] += (gx0 * gy0) * gz1 * featv;
        sA[base + 3 ][lane] += (gx0 * gy1) * gz0 * featv;
        sA[base + 4 ][lane] += (gx0 * gy1) * gz1 * featv;
        sA[base + 9 ][lane] += (gx1 * gy0) * gz0 * featv;
        sA[base + 10][lane] += (gx1 * gy0) * gz1 * featv;
        sA[base + 12][lane] += (gx1 * gy1) * gz0 * featv;
        sA[base + 13][lane] += (gx1 * gy1) * gz1 * featv;
    }
    __syncthreads();

    const int o    = lane & 31;
    const int half = lane >> 5;
    const int c_begin = half ? 14 : 0;
    const int c_end   = half ? 27 : 14;
    float acc = 0.0f;
    for (int cell = c_begin; cell < c_end; ++cell) {
        const float* __restrict__ Wrow = W + (cell * CIN) * COUT + o;
        #pragma unroll 8
        for (int f = 0; f < CIN; ++f) acc += sA[cell][f] * Wrow[f * COUT];
    }
    acc += __shfl_xor(acc, 32);
    if (lane < COUT) {
        float nn = (float)cnt;
        out[n * COUT + lane] = acc / fmaxf(nn, 1.0f) + bias[lane];
    }
}

extern "C" void kernel_launch(void* const* d_in, const int* in_sizes, int n_in,
                              void* d_out, int out_size, void* d_ws, size_t ws_size,
                              hipStream_t stream) {
    const float* feats  = (const float*)d_in[0];
    const float* points = (const float*)d_in[1];
    const float* W      = (const float*)d_in[2];
    const float* bias   = (const float*)d_in[3];
    float* out = (float*)d_out;

    // ws layout: Wt bf16 | counts | cursor | offsets | sorted | pts_s
    const size_t wt_bytes = (size_t)WT_ELEMS * sizeof(unsigned short);   // 110592
    const size_t ints     = (size_t)(GCELLS + GCELLS + GCELLS + 1 + N_PTS);
    const size_t need     = wt_bytes + ints * sizeof(int) + (size_t)3 * N_PTS * sizeof(float);

    if (ws_size >= need) {
        unsigned short* Wt = (unsigned short*)d_ws;
        int* counts  = (int*)((char*)d_ws + wt_bytes);
        int* cursor  = counts + GCELLS;
        int* offsets = cursor + GCELLS;          // GCELLS+1
        int* sorted  = offsets + GCELLS + 1;     // N_PTS
        float* pts_s = (float*)(sorted + N_PTS); // 3*N_PTS

        hipMemsetAsync(counts, 0, GCELLS * sizeof(int), stream);
        grid_count_kernel<<<(N_PTS + 255) / 256, 256, 0, stream>>>(points, counts);
        grid_scan_kernel<<<1, 1024, 0, stream>>>(counts, offsets, cursor);
        grid_scatter_kernel<<<(N_PTS + 255) / 256, 256, 0, stream>>>(points, cursor, sorted, pts_s);
        wt_transpose_kernel<<<NCELLS, 256, 0, stream>>>(W, Wt);
        cconv_grid_mfma_kernel<<<N_PTS / QB, QB * 64, 0, stream>>>(
            feats, Wt, bias, offsets, sorted, pts_s, out);
    } else {
        cconv_fused_kernel<<<N_PTS, 64, 0, stream>>>(feats, points, W, bias, out);
    }
}

// Round 9
// 133.591 us; speedup vs baseline: 1.3212x; 1.0586x over previous
//
#include <hip/hip_runtime.h>
#include <math.h>

#define N_PTS   10000
#define CIN     64
#define COUT    32
#define KCAP    32
#define RADIUSF 0.07f
#define NCELLS  27
#define QB      4      // queries per block (4 waves; wave w owns query w)
#define MAXC    48     // per-query in-radius cap (Poisson(14.4): P(>48) ~ 1e-12)
#define GRES    14     // hash grid resolution; 1/14 = 0.0714 > R = 0.07
#define GCELLS  (GRES * GRES * GRES)   // 2744
#define APAD    65     // sA row stride (floats); odd stride spreads banks
#define WT_ELEMS (NCELLS * COUT * CIN) // 55296

typedef __attribute__((ext_vector_type(8))) short         bf16x8_t;
typedef __attribute__((ext_vector_type(4))) float         f32x4_t;
typedef __attribute__((ext_vector_type(4))) unsigned int  u32x4;

__device__ __forceinline__ void cell_coords(float x, float y, float z,
                                            int& cx, int& cy, int& cz) {
    cx = (int)(x * (float)GRES); if (cx > GRES - 1) cx = GRES - 1; if (cx < 0) cx = 0;
    cy = (int)(y * (float)GRES); if (cy > GRES - 1) cy = GRES - 1; if (cy < 0) cy = 0;
    cz = (int)(z * (float)GRES); if (cz > GRES - 1) cz = GRES - 1; if (cz < 0) cz = 0;
}

// fp32 -> bf16 round-to-nearest-even, raw bits (finite inputs)
__device__ __forceinline__ unsigned int f2bf_u(float x) {
    unsigned int u = __float_as_uint(x);
    return (u + 0x7FFFu + ((u >> 16) & 1u)) >> 16;
}
__device__ __forceinline__ unsigned int pack_bf16x2(float lo, float hi) {
    return (f2bf_u(lo) & 0xFFFFu) | (f2bf_u(hi) << 16);
}

// ---- fused build kernel: block 0 = grid build (LDS hist+scan+scatter),
// ----                     blocks 1..27 = W[cell] f32->bf16 transpose
__global__ __launch_bounds__(1024) void build_fused_kernel(
    const float* __restrict__ pts,
    const float* __restrict__ W,
    int*   __restrict__ offsets,          // GCELLS+1
    int*   __restrict__ sorted,           // N_PTS
    float* __restrict__ pts_s,            // 3*N_PTS cell-sorted copies
    unsigned short* __restrict__ Wt)      // [cell][o][f] bf16
{
    __shared__ int   s_hist[GCELLS];      // counts -> cursors
    __shared__ int   s_scan[1024];
    __shared__ float tile[CIN * 33];
    const int t = threadIdx.x;

    if (blockIdx.x != 0) {
        // ---- W transpose for one cell ----
        const int cell = blockIdx.x - 1;
        for (int idx = t; idx < CIN * COUT; idx += 1024) {
            int f = idx >> 5, o = idx & 31;
            tile[f * 33 + o] = W[cell * (CIN * COUT) + idx];    // coalesced read
        }
        __syncthreads();
        for (int idx = t; idx < CIN * COUT; idx += 1024) {
            int o = idx >> 6, f = idx & 63;
            Wt[cell * (CIN * COUT) + idx] = (unsigned short)f2bf_u(tile[f * 33 + o]);
        }
        return;
    }

    // ---- block 0: histogram ----
    for (int i = t; i < GCELLS; i += 1024) s_hist[i] = 0;
    __syncthreads();
    for (int i = t; i < N_PTS; i += 1024) {
        int cx, cy, cz;
        cell_coords(pts[3 * i], pts[3 * i + 1], pts[3 * i + 2], cx, cy, cz);
        atomicAdd(&s_hist[(cx * GRES + cy) * GRES + cz], 1);
    }
    __syncthreads();

    // ---- scan (3 cells per thread, Hillis-Steele over 1024) ----
    const int c0 = t * 3;
    int v0 = (c0 + 0 < GCELLS) ? s_hist[c0 + 0] : 0;
    int v1 = (c0 + 1 < GCELLS) ? s_hist[c0 + 1] : 0;
    int v2 = (c0 + 2 < GCELLS) ? s_hist[c0 + 2] : 0;
    s_scan[t] = v0 + v1 + v2;
    __syncthreads();
    for (int d = 1; d < 1024; d <<= 1) {
        int add = (t >= d) ? s_scan[t - d] : 0;
        __syncthreads();
        s_scan[t] += add;
        __syncthreads();
    }
    int base = (t == 0) ? 0 : s_scan[t - 1];
    if (c0 + 0 < GCELLS) { offsets[c0 + 0] = base; s_hist[c0 + 0] = base; base += v0; }
    if (c0 + 1 < GCELLS) { offsets[c0 + 1] = base; s_hist[c0 + 1] = base; base += v1; }
    if (c0 + 2 < GCELLS) { offsets[c0 + 2] = base; s_hist[c0 + 2] = base; base += v2; }
    if (t == 1023) offsets[GCELLS] = s_scan[1023];
    __syncthreads();

    // ---- scatter: indices + cell-sorted point copies (bitwise) ----
    for (int i = t; i < N_PTS; i += 1024) {
        float x = pts[3 * i + 0], y = pts[3 * i + 1], z = pts[3 * i + 2];
        int cx, cy, cz;
        cell_coords(x, y, z, cx, cy, cz);
        int pos = atomicAdd(&s_hist[(cx * GRES + cy) * GRES + cz], 1);
        sorted[pos] = i;
        pts_s[3 * pos + 0] = x;
        pts_s[3 * pos + 1] = y;
        pts_s[3 * pos + 2] = z;
    }
}

// ---- main fused kernel ----
__global__ __launch_bounds__(256) void cconv_grid_mfma_kernel(
    const float* __restrict__ feats,
    const unsigned short* __restrict__ Wt,   // [27][32][64] bf16
    const float* __restrict__ bias,
    const int*   __restrict__ offsets,
    const int*   __restrict__ sorted,
    const float* __restrict__ pts_s,         // cell-sorted point copies
    float* __restrict__ out)
{
    const int tid  = threadIdx.x;
    const int lane = tid & 63;
    const int wave = tid >> 6;

    // 32480 B total -> 5 blocks/CU
    __shared__ __align__(16) float sA[QB][NCELLS][APAD];   // 28080 B (also hosts w9 overlay pre-store)
    __shared__ __align__(16) float s_pool[QB][4][MAXC];    // 3072 B: {d2,px,py,pz}; sC overlay post-barrier
    __shared__ int   s_idx[QB][MAXC];                      // 768 B
    __shared__ int   s_sel[QB][KCAP];                      // 512 B
    __shared__ int   s_cnt[QB];
    __shared__ int   s_qi[QB];
    __shared__ int   s_nn[QB];

    if (lane == 0) s_cnt[wave] = 0;

    const int q_flat = blockIdx.x * QB + wave;
    const int qi = sorted[q_flat];
    const float qx = pts_s[3 * q_flat + 0];   // == points[qi], bitwise
    const float qy = pts_s[3 * q_flat + 1];
    const float qz = pts_s[3 * q_flat + 2];
    const float sqn = qx * qx + qy * qy + qz * qz;
    const float r2 = RADIUSF * RADIUSF;

    int cx, cy, cz;
    cell_coords(qx, qy, qz, cx, cy, cz);

    // ---- Phase 1: candidate scan over neighbor cells (9 contiguous z-rows) ----
    for (int dx = -1; dx <= 1; ++dx) {
        int cxx = cx + dx;
        if (cxx < 0 || cxx > GRES - 1) continue;
        for (int dy = -1; dy <= 1; ++dy) {
            int cyy = cy + dy;
            if (cyy < 0 || cyy > GRES - 1) continue;
            int zlo = cz - 1; if (zlo < 0) zlo = 0;
            int zhi = cz + 1; if (zhi > GRES - 1) zhi = GRES - 1;
            int row = (cxx * GRES + cyy) * GRES;
            int s = offsets[row + zlo];
            int e = offsets[row + zhi + 1];
            for (int base = s; base < e; base += 64) {
                int t = base + lane;
                if (t < e) {
                    float x = pts_s[3 * t + 0];
                    float y = pts_s[3 * t + 1];
                    float z = pts_s[3 * t + 2];
                    float sqj = x * x + y * y + z * z;
                    float dot = qx * x + qy * y + qz * z;
                    float d2 = (sqn + sqj) - 2.0f * dot;   // byte-identical to ref form
                    if (d2 <= r2) {
                        int pos = atomicAdd(&s_cnt[wave], 1);
                        if (pos < MAXC) {
                            s_pool[wave][0][pos] = d2;
                            s_pool[wave][1][pos] = x;
                            s_pool[wave][2][pos] = y;
                            s_pool[wave][3][pos] = z;
                            s_idx[wave][pos] = sorted[t];
                        }
                    }
                }
            }
        }
    }

    int M = s_cnt[wave]; if (M > MAXC) M = MAXC;
    const int cnt = (M > KCAP) ? KCAP : M;
    const bool over = (M > KCAP);

    if (over) {   // exact top-32; tie-break matches lax.top_k (d2, then original index)
        if (lane < M) {
            float dc = s_pool[wave][0][lane];
            int   ic = s_idx[wave][lane];
            int rank = 0;
            for (int m = 0; m < M; ++m) {
                float dm = s_pool[wave][0][m];
                int   im = s_idx[wave][m];
                rank += (dm < dc || (dm == dc && im < ic)) ? 1 : 0;
            }
            if (rank < KCAP) s_sel[wave][rank] = lane;   // store SLOT
        }
    }
    if (lane == 0) { s_qi[wave] = qi; s_nn[wave] = cnt; }

    // ---- Phase 2a: per-neighbor trilinear weights computed ONCE, in parallel ----
    // lane k handles rank-k neighbor; stash 9 axis-weights + feats row base in the
    // sA region (dead until the post-loop store). Wave-local LDS is in-order.
    float* w9w = (float*)&sA[wave][0][0];   // uses first 32*12=384 of 1755 floats
    if (lane < cnt) {
        int slot = over ? s_sel[wave][lane] : lane;
        float x = s_pool[wave][1][slot];
        float y = s_pool[wave][2][slot];
        float z = s_pool[wave][3][slot];
        int   j = s_idx[wave][slot];
        float rx = (x - qx) / RADIUSF;
        float ry = (y - qy) / RADIUSF;
        float rz = (z - qz) / RADIUSF;
        float l2 = sqrtf(rx * rx + ry * ry + rz * rz);
        float ax = fabsf(rx), ay = fabsf(ry), az = fabsf(rz);
        float linf = fmaxf(fmaxf(ax, ay), az);
        float s = (linf > 0.0f) ? (l2 / fmaxf(linf, 1e-12f)) : 0.0f;
        float tx = rx * s, ty = ry * s, tz = rz * s;
        float cxf = (tx + 1.0f) * 0.5f * 2.0f;
        float cyf = (ty + 1.0f) * 0.5f * 2.0f;
        float czf = (tz + 1.0f) * 0.5f * 2.0f;
        float c0x = fminf(fmaxf(floorf(cxf), 0.0f), 1.0f);
        float c0y = fminf(fmaxf(floorf(cyf), 0.0f), 1.0f);
        float c0z = fminf(fmaxf(floorf(czf), 0.0f), 1.0f);
        float fx = cxf - c0x;
        float fy = cyf - c0y;
        float fz = czf - c0z;
        int i0 = (int)c0x, i1 = (int)c0y, i2 = (int)c0z;
        float gx0 = 1.0f - fx, gx1 = fx;
        float gy0 = 1.0f - fy, gy1 = fy;
        float gz0 = 1.0f - fz, gz1 = fz;
        float* wp = w9w + lane * 12;
        wp[0] = i0 ? 0.0f : gx0;  wp[1] = i0 ? gx0 : gx1;  wp[2] = i0 ? gx1 : 0.0f;
        wp[3] = i1 ? 0.0f : gy0;  wp[4] = i1 ? gy0 : gy1;  wp[5] = i1 ? gy1 : 0.0f;
        wp[6] = i2 ? 0.0f : gz0;  wp[7] = i2 ? gz0 : gz1;  wp[8] = i2 ? gz1 : 0.0f;
        wp[9] = __int_as_float(j * CIN);
    }

    // ---- Phase 2b: register-accumulated scatter (lane = feature) ----
    float a[NCELLS];
    #pragma unroll
    for (int c = 0; c < NCELLS; ++c) a[c] = 0.0f;

    for (int k = 0; k < cnt; ++k) {
        const float* wp = w9w + k * 12;       // broadcast LDS reads
        float wxv[3] = {wp[0], wp[1], wp[2]};
        float wyv[3] = {wp[3], wp[4], wp[5]};
        float wz0 = wp[6], wz1 = wp[7], wz2 = wp[8];
        int jbase = __float_as_int(wp[9]);
        float featv = feats[jbase + lane];    // coalesced
        float pzv[3] = {wz0 * featv, wz1 * featv, wz2 * featv};
        #pragma unroll
        for (int ci = 0; ci < 3; ++ci) {
            #pragma unroll
            for (int cj = 0; cj < 3; ++cj) {
                float wxy = wxv[ci] * wyv[cj];
                #pragma unroll
                for (int ck = 0; ck < 3; ++ck) {
                    a[ci * 9 + cj * 3 + ck] = fmaf(wxy, pzv[ck], a[ci * 9 + cj * 3 + ck]);
                }
            }
        }
    }
    #pragma unroll
    for (int c = 0; c < NCELLS; ++c) sA[wave][c][lane] = a[c];   // overwrites w9 (dead)
    __syncthreads();   // all waves' sA / s_qi / s_nn now visible; pool now dead

    // ---- Phase 3: MFMA contraction  out[4x32] = A[4x1728] * W[1728x32] ----
    float (*sC)[QB][COUT] = (float (*)[QB][COUT])&s_pool[0][0][0];   // overlay (2048 <= 3072 B)
    f32x4_t acc0 = {0.f, 0.f, 0.f, 0.f};
    f32x4_t acc1 = {0.f, 0.f, 0.f, 0.f};
    const int r  = lane & 15;
    const int kg = lane >> 4;
    for (int s = wave; s < 2 * NCELLS; s += QB) {   // 54 K-steps, round-robin
        const int c  = s >> 1;
        const int f0 = (s & 1) << 5;
        bf16x8_t af = {};
        if (r < QB) {
            const float* Ap = &sA[r][c][f0 + kg * 8];
            u32x4 au;
            #pragma unroll
            for (int p = 0; p < 4; ++p) au[p] = pack_bf16x2(Ap[2 * p], Ap[2 * p + 1]);
            af = __builtin_bit_cast(bf16x8_t, au);
        }
        const unsigned short* wp0 = Wt + ((c * COUT + r     ) * CIN + f0 + kg * 8);
        const unsigned short* wp1 = Wt + ((c * COUT + 16 + r) * CIN + f0 + kg * 8);
        bf16x8_t bf0 = *(const bf16x8_t*)wp0;
        bf16x8_t bf1 = *(const bf16x8_t*)wp1;
        acc0 = __builtin_amdgcn_mfma_f32_16x16x32_bf16(af, bf0, acc0, 0, 0, 0);
        acc1 = __builtin_amdgcn_mfma_f32_16x16x32_bf16(af, bf1, acc1, 0, 0, 0);
    }
    if (lane < 16) {
        #pragma unroll
        for (int j = 0; j < QB; ++j) {
            sC[wave][j][lane]      = acc0[j];
            sC[wave][j][16 + lane] = acc1[j];
        }
    }
    __syncthreads();

    if (tid < QB * COUT) {
        int q = tid >> 5, o = tid & 31;
        float v = sC[0][q][o] + sC[1][q][o] + sC[2][q][o] + sC[3][q][o];
        float nn = (float)s_nn[q];
        out[s_qi[q] * COUT + o] = v / fmaxf(nn, 1.0f) + bias[o];
    }
}

// ---- fallback (validated Round-3 kernel) if workspace is too small ----
__global__ __launch_bounds__(64) void cconv_fused_kernel(
    const float* __restrict__ feats,
    const float* __restrict__ points,
    const float* __restrict__ W,
    const float* __restrict__ bias,
    float* __restrict__ out)
{
    const int n    = blockIdx.x;
    const int lane = threadIdx.x;

    __shared__ float sA[NCELLS][CIN];
    __shared__ float s_d2[128];
    __shared__ int   s_idx[128];
    __shared__ int   s_rank[128];
    __shared__ int   s_sel[KCAP];
    __shared__ int   s_cnt;

    if (lane == 0) s_cnt = 0;
    for (int c = lane; c < NCELLS * CIN; c += 64) ((float*)sA)[c] = 0.0f;
    __syncthreads();

    const float qx = points[3 * n + 0];
    const float qy = points[3 * n + 1];
    const float qz = points[3 * n + 2];
    const float sqn = qx * qx + qy * qy + qz * qz;
    const float r2 = RADIUSF * RADIUSF;

    for (int j = lane; j < N_PTS; j += 64) {
        float x = points[3 * j + 0];
        float y = points[3 * j + 1];
        float z = points[3 * j + 2];
        float sqj = x * x + y * y + z * z;
        float dot = qx * x + qy * y + qz * z;
        float d2 = (sqn + sqj) - 2.0f * dot;
        if (d2 <= r2) {
            int pos = atomicAdd(&s_cnt, 1);
            if (pos < 128) { s_d2[pos] = d2; s_idx[pos] = j; }
        }
    }
    __syncthreads();

    int M = s_cnt; if (M > 128) M = 128;
    int cnt;
    if (M > KCAP) {
        for (int c = lane; c < M; c += 64) {
            float dc = s_d2[c]; int ic = s_idx[c]; int rank = 0;
            for (int m = 0; m < M; ++m) {
                float dm = s_d2[m]; int im = s_idx[m];
                rank += (dm < dc || (dm == dc && im < ic)) ? 1 : 0;
            }
            s_rank[c] = rank;
        }
        __syncthreads();
        for (int c = lane; c < M; c += 64) {
            int r = s_rank[c];
            if (r < KCAP) s_sel[r] = s_idx[c];
        }
        __syncthreads();
        cnt = KCAP;
    } else cnt = M;
    const int* nbr = (M > KCAP) ? s_sel : s_idx;

    for (int k = 0; k < cnt; ++k) {
        int j = nbr[k];
        float x = points[3 * j + 0];
        float y = points[3 * j + 1];
        float z = points[3 * j + 2];
        float rx = (x - qx) / RADIUSF;
        float ry = (y - qy) / RADIUSF;
        float rz = (z - qz) / RADIUSF;
        float l2 = sqrtf(rx * rx + ry * ry + rz * rz);
        float ax = fabsf(rx), ay = fabsf(ry), az = fabsf(rz);
        float linf = fmaxf(fmaxf(ax, ay), az);
        float s = (linf > 0.0f) ? (l2 / fmaxf(linf, 1e-12f)) : 0.0f;
        float tx = rx * s, ty = ry * s, tz = rz * s;
        float cxf = (tx + 1.0f) * 0.5f * 2.0f;
        float cyf = (ty + 1.0f) * 0.5f * 2.0f;
        float czf = (tz + 1.0f) * 0.5f * 2.0f;
        float c0x = fminf(fmaxf(floorf(cxf), 0.0f), 1.0f);
        float c0y = fminf(fmaxf(floorf(cyf), 0.0f), 1.0f);
        float c0z = fminf(fmaxf(floorf(czf), 0.0f), 1.0f);
        float fx = cxf - c0x, fy = cyf - c0y, fz = czf - c0z;
        int i0 = (int)c0x, i1 = (int)c0y, i2 = (int)c0z;
        int base = i0 * 9 + i1 * 3 + i2;
        float gx0 = 1.0f - fx, gx1 = fx;
        float gy0 = 1.0f - fy, gy1 = fy;
        float gz0 = 1.0f - fz, gz1 = fz;
        float featv = feats[j * CIN + lane];
        sA[base + 0 ][lane] += (gx0 * gy0) * gz0 * featv;
        sA[base + 1 ][lane] += (gx0 * gy0) * gz1 * featv;
        sA[base + 3 ][lane] += (gx0 * gy1) * gz0 * featv;
        sA[base + 4 ][lane] += (gx0 * gy1) * gz1 * featv;
        sA[base + 9 ][lane] += (gx1 * gy0) * gz0 * featv;
        sA[base + 10][lane] += (gx1 * gy0) * gz1 * featv;
        sA[base + 12][lane] += (gx1 * gy1) * gz0 * featv;
        sA[base + 13][lane] += (gx1 * gy1) * gz1 * featv;
    }
    __syncthreads();

    const int o    = lane & 31;
    const int half = lane >> 5;
    const int c_begin = half ? 14 : 0;
    const int c_end   = half ? 27 : 14;
    float acc = 0.0f;
    for (int cell = c_begin; cell < c_end; ++cell) {
        const float* __restrict__ Wrow = W + (cell * CIN) * COUT + o;
        #pragma unroll 8
        for (int f = 0; f < CIN; ++f) acc += sA[cell][f] * Wrow[f * COUT];
    }
    acc += __shfl_xor(acc, 32);
    if (lane < COUT) {
        float nn = (float)cnt;
        out[n * COUT + lane] = acc / fmaxf(nn, 1.0f) + bias[lane];
    }
}

extern "C" void kernel_launch(void* const* d_in, const int* in_sizes, int n_in,
                              void* d_out, int out_size, void* d_ws, size_t ws_size,
                              hipStream_t stream) {
    const float* feats  = (const float*)d_in[0];
    const float* points = (const float*)d_in[1];
    const float* W      = (const float*)d_in[2];
    const float* bias   = (const float*)d_in[3];
    float* out = (float*)d_out;

    // ws layout: Wt bf16 | offsets | sorted | pts_s
    const size_t wt_bytes = (size_t)WT_ELEMS * sizeof(unsigned short);   // 110592
    const size_t need     = wt_bytes + (size_t)(GCELLS + 1 + N_PTS) * sizeof(int)
                          + (size_t)3 * N_PTS * sizeof(float);

    if (ws_size >= need) {
        unsigned short* Wt = (unsigned short*)d_ws;
        int* offsets = (int*)((char*)d_ws + wt_bytes);   // GCELLS+1
        int* sorted  = offsets + GCELLS + 1;             // N_PTS
        float* pts_s = (float*)(sorted + N_PTS);         // 3*N_PTS

        build_fused_kernel<<<1 + NCELLS, 1024, 0, stream>>>(points, W, offsets, sorted, pts_s, Wt);
        cconv_grid_mfma_kernel<<<N_PTS / QB, QB * 64, 0, stream>>>(
            feats, Wt, bias, offsets, sorted, pts_s, out);
    } else {
        cconv_fused_kernel<<<N_PTS, 64, 0, stream>>>(feats, points, W, bias, out);
    }
}

// Round 10
// 120.844 us; speedup vs baseline: 1.4606x; 1.1055x over previous
//
#include <hip/hip_runtime.h>
#include <math.h>

#define N_PTS   10000
#define CIN     64
#define COUT    32
#define KCAP    32
#define RADIUSF 0.07f
#define NCELLS  27
#define QB      4      // queries per block (4 waves; wave w owns query w)
#define MAXC    48     // per-query in-radius cap (Poisson(14.4): P(>48) ~ 1e-12)
#define GRES    14     // hash grid resolution; 1/14 = 0.0714 > R = 0.07
#define GCELLS  (GRES * GRES * GRES)   // 2744
#define CPAD    72     // sA bf16 row stride: 144 B = 9*16 -> b128-aligned, banks spread
#define NBBLD   28     // build blocks: replicated hist, striped scatter
#define WT_ELEMS (NCELLS * COUT * CIN) // 55296

typedef __attribute__((ext_vector_type(8))) short         bf16x8_t;
typedef __attribute__((ext_vector_type(4))) float         f32x4_t;

__device__ __forceinline__ void cell_coords(float x, float y, float z,
                                            int& cx, int& cy, int& cz) {
    cx = (int)(x * (float)GRES); if (cx > GRES - 1) cx = GRES - 1; if (cx < 0) cx = 0;
    cy = (int)(y * (float)GRES); if (cy > GRES - 1) cy = GRES - 1; if (cy < 0) cy = 0;
    cz = (int)(z * (float)GRES); if (cz > GRES - 1) cz = GRES - 1; if (cz < 0) cz = 0;
}

// fp32 -> bf16 round-to-nearest-even, raw bits (finite inputs)
__device__ __forceinline__ unsigned int f2bf_u(float x) {
    unsigned int u = __float_as_uint(x);
    return (u + 0x7FFFu + ((u >> 16) & 1u)) >> 16;
}

// ---- build kernel (28 blocks x 1024): every block replicates LDS hist+scan
// ---- (L2-hot reads); block 0 writes offsets; each block scatters a stripe via
// ---- global cursor atomics; blocks 1..27 also transpose W[cell] -> bf16.
__global__ __launch_bounds__(1024) void build_rep_kernel(
    const float* __restrict__ pts,
    const float* __restrict__ W,
    int*   __restrict__ offsets,          // GCELLS+1
    int*   __restrict__ sorted,           // N_PTS
    int*   __restrict__ cursor,           // GCELLS (pre-zeroed)
    float* __restrict__ pts_s,            // 3*N_PTS cell-sorted copies
    unsigned short* __restrict__ Wt)      // [cell][o][f] bf16
{
    __shared__ int   s_hist[GCELLS];
    __shared__ int   s_scan[1024];
    __shared__ float tile[CIN * 33];
    const int t = threadIdx.x;
    const int b = blockIdx.x;

    // ---- replicated histogram ----
    for (int i = t; i < GCELLS; i += 1024) s_hist[i] = 0;
    __syncthreads();
    for (int i = t; i < N_PTS; i += 1024) {
        int cx, cy, cz;
        cell_coords(pts[3 * i], pts[3 * i + 1], pts[3 * i + 2], cx, cy, cz);
        atomicAdd(&s_hist[(cx * GRES + cy) * GRES + cz], 1);
    }
    __syncthreads();

    // ---- replicated scan (3 cells/thread, Hillis-Steele over 1024) ----
    const int c0 = t * 3;
    int v0 = (c0 + 0 < GCELLS) ? s_hist[c0 + 0] : 0;
    int v1 = (c0 + 1 < GCELLS) ? s_hist[c0 + 1] : 0;
    int v2 = (c0 + 2 < GCELLS) ? s_hist[c0 + 2] : 0;
    s_scan[t] = v0 + v1 + v2;
    __syncthreads();
    for (int d = 1; d < 1024; d <<= 1) {
        int add = (t >= d) ? s_scan[t - d] : 0;
        __syncthreads();
        s_scan[t] += add;
        __syncthreads();
    }
    int base = (t == 0) ? 0 : s_scan[t - 1];
    if (c0 + 0 < GCELLS) { s_hist[c0 + 0] = base; base += v0; }
    if (c0 + 1 < GCELLS) { s_hist[c0 + 1] = base; base += v1; }
    if (c0 + 2 < GCELLS) { s_hist[c0 + 2] = base; base += v2; }
    __syncthreads();

    // ---- block 0 publishes offsets ----
    if (b == 0) {
        for (int i = t; i < GCELLS; i += 1024) offsets[i] = s_hist[i];
        if (t == 0) offsets[GCELLS] = N_PTS;
    }

    // ---- striped scatter (parallel across blocks, global cursor atomics) ----
    const int per = (N_PTS + NBBLD - 1) / NBBLD;   // 358
    const int lo = b * per;
    const int hi = (lo + per < N_PTS) ? lo + per : N_PTS;
    for (int i = lo + t; i < hi; i += 1024) {
        float x = pts[3 * i + 0], y = pts[3 * i + 1], z = pts[3 * i + 2];
        int cx, cy, cz;
        cell_coords(x, y, z, cx, cy, cz);
        int cell = (cx * GRES + cy) * GRES + cz;
        int pos = s_hist[cell] + atomicAdd(&cursor[cell], 1);
        sorted[pos] = i;
        pts_s[3 * pos + 0] = x;   // bitwise copies -> d2 stays byte-identical
        pts_s[3 * pos + 1] = y;
        pts_s[3 * pos + 2] = z;
    }

    // ---- blocks 1..27: W transpose for cell b-1 ----
    if (b >= 1) {
        const int cell = b - 1;
        __syncthreads();
        for (int idx = t; idx < CIN * COUT; idx += 1024) {
            int f = idx >> 5, o = idx & 31;
            tile[f * 33 + o] = W[cell * (CIN * COUT) + idx];    // coalesced read
        }
        __syncthreads();
        for (int idx = t; idx < CIN * COUT; idx += 1024) {
            int o = idx >> 6, f = idx & 63;
            Wt[cell * (CIN * COUT) + idx] = (unsigned short)f2bf_u(tile[f * 33 + o]);
        }
    }
}

// ---- main fused kernel ----
__global__ __launch_bounds__(256) void cconv_grid_mfma_kernel(
    const float* __restrict__ feats,
    const unsigned short* __restrict__ Wt,   // [27][32][64] bf16
    const float* __restrict__ bias,
    const int*   __restrict__ offsets,
    const int*   __restrict__ sorted,
    const float* __restrict__ pts_s,         // cell-sorted point copies
    float* __restrict__ out)
{
    const int tid  = threadIdx.x;
    const int lane = tid & 63;
    const int wave = tid >> 6;

    // ~19.9 KB total -> 8 blocks/CU
    __shared__ __align__(16) unsigned short sAb[QB][NCELLS][CPAD];  // 15552 B bf16 A
    __shared__ __align__(16) float s_pool[QB][4][MAXC];             // 3072 B {d2,x,y,z}; sC overlay later
    __shared__ int   s_idx[QB][MAXC];                               // 768 B
    __shared__ int   s_sel[QB][KCAP];                               // 512 B
    __shared__ int   s_cnt[QB];
    __shared__ int   s_qi[QB];
    __shared__ int   s_nn[QB];

    if (lane == 0) s_cnt[wave] = 0;

    const int q_flat = blockIdx.x * QB + wave;
    const int qi = sorted[q_flat];
    const float qx = pts_s[3 * q_flat + 0];   // == points[qi], bitwise
    const float qy = pts_s[3 * q_flat + 1];
    const float qz = pts_s[3 * q_flat + 2];
    const float sqn = qx * qx + qy * qy + qz * qz;
    const float r2 = RADIUSF * RADIUSF;

    int cx, cy, cz;
    cell_coords(qx, qy, qz, cx, cy, cz);

    // ---- Phase 1: flattened candidate scan over up to 9 z-row segments ----
    int zlo = cz - 1; if (zlo < 0) zlo = 0;
    int zhi = cz + 1; if (zhi > GRES - 1) zhi = GRES - 1;
    int ss[9], sl[9];
    #pragma unroll
    for (int dxi = 0; dxi < 3; ++dxi) {
        #pragma unroll
        for (int dyi = 0; dyi < 3; ++dyi) {
            const int ii = dxi * 3 + dyi;            // compile-time slot
            int cxx = cx + dxi - 1, cyy = cy + dyi - 1;
            bool ok = (cxx >= 0) && (cxx <= GRES - 1) && (cyy >= 0) && (cyy <= GRES - 1);
            int row = ((ok ? cxx : 0) * GRES + (ok ? cyy : 0)) * GRES;
            int s = offsets[row + zlo];
            int e = offsets[row + zhi + 1];
            ss[ii] = s;
            sl[ii] = ok ? (e - s) : 0;
        }
    }
    int cum[10];
    cum[0] = 0;
    #pragma unroll
    for (int ii = 0; ii < 9; ++ii) cum[ii + 1] = cum[ii] + sl[ii];
    const int T = cum[9];

    for (int t = lane; t < T; t += 64) {
        int gidx = 0;
        #pragma unroll
        for (int ii = 0; ii < 9; ++ii) {
            bool in = (t >= cum[ii]) && (t < cum[ii + 1]);
            int cand = ss[ii] + (t - cum[ii]);
            gidx = in ? cand : gidx;
        }
        float x = pts_s[3 * gidx + 0];
        float y = pts_s[3 * gidx + 1];
        float z = pts_s[3 * gidx + 2];
        float sqj = x * x + y * y + z * z;
        float dot = qx * x + qy * y + qz * z;
        float d2 = (sqn + sqj) - 2.0f * dot;   // byte-identical to ref form
        if (d2 <= r2) {
            int pos = atomicAdd(&s_cnt[wave], 1);
            if (pos < MAXC) {
                s_pool[wave][0][pos] = d2;
                s_pool[wave][1][pos] = x;
                s_pool[wave][2][pos] = y;
                s_pool[wave][3][pos] = z;
                s_idx[wave][pos] = sorted[gidx];
            }
        }
    }

    int M = s_cnt[wave]; if (M > MAXC) M = MAXC;
    const int cnt = (M > KCAP) ? KCAP : M;
    const bool over = (M > KCAP);

    if (over) {   // exact top-32; tie-break matches lax.top_k (d2, then original index)
        if (lane < M) {
            float dc = s_pool[wave][0][lane];
            int   ic = s_idx[wave][lane];
            int rank = 0;
            for (int m = 0; m < M; ++m) {
                float dm = s_pool[wave][0][m];
                int   im = s_idx[wave][m];
                rank += (dm < dc || (dm == dc && im < ic)) ? 1 : 0;
            }
            if (rank < KCAP) s_sel[wave][rank] = lane;   // store SLOT
        }
    }
    if (lane == 0) { s_qi[wave] = qi; s_nn[wave] = cnt; }

    // ---- Phase 2a: per-neighbor trilinear weights computed ONCE, in parallel ----
    // lane k handles rank-k neighbor; stash 9 axis-weights + feats row base in the
    // sAb region (dead until the post-loop store). Wave-local LDS is in-order.
    float* w9w = (float*)&sAb[wave][0][0];   // 32*12*4 = 1536 B < 3888 B per-wave region
    if (lane < cnt) {
        int slot = over ? s_sel[wave][lane] : lane;
        float x = s_pool[wave][1][slot];
        float y = s_pool[wave][2][slot];
        float z = s_pool[wave][3][slot];
        int   j = s_idx[wave][slot];
        float rx = (x - qx) / RADIUSF;
        float ry = (y - qy) / RADIUSF;
        float rz = (z - qz) / RADIUSF;
        float l2 = sqrtf(rx * rx + ry * ry + rz * rz);
        float ax = fabsf(rx), ay = fabsf(ry), az = fabsf(rz);
        float linf = fmaxf(fmaxf(ax, ay), az);
        float s = (linf > 0.0f) ? (l2 / fmaxf(linf, 1e-12f)) : 0.0f;
        float tx = rx * s, ty = ry * s, tz = rz * s;
        float cxf = (tx + 1.0f) * 0.5f * 2.0f;
        float cyf = (ty + 1.0f) * 0.5f * 2.0f;
        float czf = (tz + 1.0f) * 0.5f * 2.0f;
        float c0x = fminf(fmaxf(floorf(cxf), 0.0f), 1.0f);
        float c0y = fminf(fmaxf(floorf(cyf), 0.0f), 1.0f);
        float c0z = fminf(fmaxf(floorf(czf), 0.0f), 1.0f);
        float fx = cxf - c0x;
        float fy = cyf - c0y;
        float fz = czf - c0z;
        int i0 = (int)c0x, i1 = (int)c0y, i2 = (int)c0z;
        float gx0 = 1.0f - fx, gx1 = fx;
        float gy0 = 1.0f - fy, gy1 = fy;
        float gz0 = 1.0f - fz, gz1 = fz;
        float* wp = w9w + lane * 12;
        wp[0] = i0 ? 0.0f : gx0;  wp[1] = i0 ? gx0 : gx1;  wp[2] = i0 ? gx1 : 0.0f;
        wp[3] = i1 ? 0.0f : gy0;  wp[4] = i1 ? gy0 : gy1;  wp[5] = i1 ? gy1 : 0.0f;
        wp[6] = i2 ? 0.0f : gz0;  wp[7] = i2 ? gz0 : gz1;  wp[8] = i2 ? gz1 : 0.0f;
        wp[9] = __int_as_float(j * CIN);
    }

    // ---- Phase 2b: register-accumulated scatter (lane = feature), feats prefetch ----
    float a[NCELLS];
    #pragma unroll
    for (int c = 0; c < NCELLS; ++c) a[c] = 0.0f;

    if (cnt > 0) {
        int jb = __float_as_int(w9w[9]);
        float fv = feats[jb + lane];
        for (int k = 0; k < cnt; ++k) {
            const float* wp = w9w + k * 12;        // broadcast LDS reads
            float wxv[3] = {wp[0], wp[1], wp[2]};
            float wyv[3] = {wp[3], wp[4], wp[5]};
            float wz0 = wp[6], wz1 = wp[7], wz2 = wp[8];
            float fv_cur = fv;
            if (k + 1 < cnt) {                     // prefetch next row
                int jb2 = __float_as_int(w9w[(k + 1) * 12 + 9]);
                fv = feats[jb2 + lane];
            }
            float pzv[3] = {wz0 * fv_cur, wz1 * fv_cur, wz2 * fv_cur};
            #pragma unroll
            for (int ci = 0; ci < 3; ++ci) {
                #pragma unroll
                for (int cj = 0; cj < 3; ++cj) {
                    float wxy = wxv[ci] * wyv[cj];
                    #pragma unroll
                    for (int ck = 0; ck < 3; ++ck) {
                        a[ci * 9 + cj * 3 + ck] = fmaf(wxy, pzv[ck], a[ci * 9 + cj * 3 + ck]);
                    }
                }
            }
        }
    }
    // store bf16 A (overwrites w9w region - dead now). 2-byte writes, 2-way banks = free.
    #pragma unroll
    for (int c = 0; c < NCELLS; ++c) sAb[wave][c][lane] = (unsigned short)f2bf_u(a[c]);
    __syncthreads();   // all waves' sAb / s_qi / s_nn now visible; s_pool now dead

    // ---- Phase 3: MFMA contraction  out[4x32] = A[4x1728] * W[1728x32] ----
    float (*sC)[QB][COUT] = (float (*)[QB][COUT])&s_pool[0][0][0];   // overlay (2048 <= 3072 B)
    f32x4_t acc0 = {0.f, 0.f, 0.f, 0.f};
    f32x4_t acc1 = {0.f, 0.f, 0.f, 0.f};
    const int r  = lane & 15;
    const int kg = lane >> 4;
    for (int s = wave; s < 2 * NCELLS; s += QB) {   // 54 K-steps, round-robin
        const int c  = s >> 1;
        const int f0 = (s & 1) << 5;
        bf16x8_t af = {};
        if (r < QB) af = *(const bf16x8_t*)&sAb[r][c][f0 + kg * 8];   // one ds_read_b128
        const unsigned short* wp0 = Wt + ((c * COUT + r     ) * CIN + f0 + kg * 8);
        const unsigned short* wp1 = Wt + ((c * COUT + 16 + r) * CIN + f0 + kg * 8);
        bf16x8_t bf0 = *(const bf16x8_t*)wp0;
        bf16x8_t bf1 = *(const bf16x8_t*)wp1;
        acc0 = __builtin_amdgcn_mfma_f32_16x16x32_bf16(af, bf0, acc0, 0, 0, 0);
        acc1 = __builtin_amdgcn_mfma_f32_16x16x32_bf16(af, bf1, acc1, 0, 0, 0);
    }
    if (lane < 16) {
        #pragma unroll
        for (int j = 0; j < QB; ++j) {
            sC[wave][j][lane]      = acc0[j];
            sC[wave][j][16 + lane] = acc1[j];
        }
    }
    __syncthreads();

    if (tid < QB * COUT) {
        int q = tid >> 5, o = tid & 31;
        float v = sC[0][q][o] + sC[1][q][o] + sC[2][q][o] + sC[3][q][o];
        float nn = (float)s_nn[q];
        out[s_qi[q] * COUT + o] = v / fmaxf(nn, 1.0f) + bias[o];
    }
}

// ---- fallback (validated Round-3 kernel) if workspace is too small ----
__global__ __launch_bounds__(64) void cconv_fused_kernel(
    const float* __restrict__ feats,
    const float* __restrict__ points,
    const float* __restrict__ W,
    const float* __restrict__ bias,
    float* __restrict__ out)
{
    const int n    = blockIdx.x;
    const int lane = threadIdx.x;

    __shared__ float sA[NCELLS][CIN];
    __shared__ float s_d2[128];
    __shared__ int   s_idx[128];
    __shared__ int   s_rank[128];
    __shared__ int   s_sel[KCAP];
    __shared__ int   s_cnt;

    if (lane == 0) s_cnt = 0;
    for (int c = lane; c < NCELLS * CIN; c += 64) ((float*)sA)[c] = 0.0f;
    __syncthreads();

    const float qx = points[3 * n + 0];
    const float qy = points[3 * n + 1];
    const float qz = points[3 * n + 2];
    const float sqn = qx * qx + qy * qy + qz * qz;
    const float r2 = RADIUSF * RADIUSF;

    for (int j = lane; j < N_PTS; j += 64) {
        float x = points[3 * j + 0];
        float y = points[3 * j + 1];
        float z = points[3 * j + 2];
        float sqj = x * x + y * y + z * z;
        float dot = qx * x + qy * y + qz * z;
        float d2 = (sqn + sqj) - 2.0f * dot;
        if (d2 <= r2) {
            int pos = atomicAdd(&s_cnt, 1);
            if (pos < 128) { s_d2[pos] = d2; s_idx[pos] = j; }
        }
    }
    __syncthreads();

    int M = s_cnt; if (M > 128) M = 128;
    int cnt;
    if (M > KCAP) {
        for (int c = lane; c < M; c += 64) {
            float dc = s_d2[c]; int ic = s_idx[c]; int rank = 0;
            for (int m = 0; m < M; ++m) {
                float dm = s_d2[m]; int im = s_idx[m];
                rank += (dm < dc || (dm == dc && im < ic)) ? 1 : 0;
            }
            s_rank[c] = rank;
        }
        __syncthreads();
        for (int c = lane; c < M; c += 64) {
            int r = s_rank[c];
            if (r < KCAP) s_sel[r] = s_idx[c];
        }
        __syncthreads();
        cnt = KCAP;
    } else cnt = M;
    const int* nbr = (M > KCAP) ? s_sel : s_idx;

    for (int k = 0; k < cnt; ++k) {
        int j = nbr[k];
        float x = points[3 * j + 0];
        float y = points[3 * j + 1];
        float z = points[3 * j + 2];
        float rx = (x - qx) / RADIUSF;
        float ry = (y - qy) / RADIUSF;
        float rz = (z - qz) / RADIUSF;
        float l2 = sqrtf(rx * rx + ry * ry + rz * rz);
        float ax = fabsf(rx), ay = fabsf(ry), az = fabsf(rz);
        float linf = fmaxf(fmaxf(ax, ay), az);
        float s = (linf > 0.0f) ? (l2 / fmaxf(linf, 1e-12f)) : 0.0f;
        float tx = rx * s, ty = ry * s, tz = rz * s;
        float cxf = (tx + 1.0f) * 0.5f * 2.0f;
        float cyf = (ty + 1.0f) * 0.5f * 2.0f;
        float czf = (tz + 1.0f) * 0.5f * 2.0f;
        float c0x = fminf(fmaxf(floorf(cxf), 0.0f), 1.0f);
        float c0y = fminf(fmaxf(floorf(cyf), 0.0f), 1.0f);
        float c0z = fminf(fmaxf(floorf(czf), 0.0f), 1.0f);
        float fx = cxf - c0x, fy = cyf - c0y, fz = czf - c0z;
        int i0 = (int)c0x, i1 = (int)c0y, i2 = (int)c0z;
        int base = i0 * 9 + i1 * 3 + i2;
        float gx0 = 1.0f - fx, gx1 = fx;
        float gy0 = 1.0f - fy, gy1 = fy;
        float gz0 = 1.0f - fz, gz1 = fz;
        float featv = feats[j * CIN + lane];
        sA[base + 0 ][lane] += (gx0 * gy0) * gz0 * featv;
        sA[base + 1 ][lane] += (gx0 * gy0) * gz1 * featv;
        sA[base + 3 ][lane] += (gx0 * gy1) * gz0 * featv;
        sA[base + 4 ][lane] += (gx0 * gy1) * gz1 * featv;
        sA[base + 9 ][lane] += (gx1 * gy0) * gz0 * featv;
        sA[base + 10][lane] += (gx1 * gy0) * gz1 * featv;
        sA[base + 12][lane] += (gx1 * gy1) * gz0 * featv;
        sA[base + 13][lane] += (gx1 * gy1) * gz1 * featv;
    }
    __syncthreads();

    const int o    = lane & 31;
    const int half = lane >> 5;
    const int c_begin = half ? 14 : 0;
    const int c_end   = half ? 27 : 14;
    float acc = 0.0f;
    for (int cell = c_begin; cell < c_end; ++cell) {
        const float* __restrict__ Wrow = W + (cell * CIN) * COUT + o;
        #pragma unroll 8
        for (int f = 0; f < CIN; ++f) acc += sA[cell][f] * Wrow[f * COUT];
    }
    acc += __shfl_xor(acc, 32);
    if (lane < COUT) {
        float nn = (float)cnt;
        out[n * COUT + lane] = acc / fmaxf(nn, 1.0f) + bias[lane];
    }
}

extern "C" void kernel_launch(void* const* d_in, const int* in_sizes, int n_in,
                              void* d_out, int out_size, void* d_ws, size_t ws_size,
                              hipStream_t stream) {
    const float* feats  = (const float*)d_in[0];
    const float* points = (const float*)d_in[1];
    const float* W      = (const float*)d_in[2];
    const float* bias   = (const float*)d_in[3];
    float* out = (float*)d_out;

    // ws layout: Wt bf16 | offsets | sorted | cursor | pts_s
    const size_t wt_bytes = (size_t)WT_ELEMS * sizeof(unsigned short);   // 110592
    const size_t need     = wt_bytes
                          + (size_t)(GCELLS + 1 + N_PTS + GCELLS) * sizeof(int)
                          + (size_t)3 * N_PTS * sizeof(float);

    if (ws_size >= need) {
        unsigned short* Wt = (unsigned short*)d_ws;
        int* offsets = (int*)((char*)d_ws + wt_bytes);   // GCELLS+1
        int* sorted  = offsets + GCELLS + 1;             // N_PTS
        int* cursor  = sorted + N_PTS;                   // GCELLS
        float* pts_s = (float*)(cursor + GCELLS);        // 3*N_PTS

        hipMemsetAsync(cursor, 0, GCELLS * sizeof(int), stream);
        build_rep_kernel<<<NBBLD, 1024, 0, stream>>>(points, W, offsets, sorted, cursor, pts_s, Wt);
        cconv_grid_mfma_kernel<<<N_PTS / QB, QB * 64, 0, stream>>>(
            feats, Wt, bias, offsets, sorted, pts_s, out);
    } else {
        cconv_fused_kernel<<<N_PTS, 64, 0, stream>>>(feats, points, W, bias, out);
    }
}

// Round 11
// 115.338 us; speedup vs baseline: 1.5303x; 1.0477x over previous
//
#include <hip/hip_runtime.h>
#include <math.h>

#define N_PTS   10000
#define CIN     64
#define COUT    32
#define KCAP    32
#define RADIUSF 0.07f
#define NCELLS  27
#define QB      4      // queries per block (4 waves; wave w owns query w)
#define MAXC    48     // per-query in-radius cap (Poisson(14.4): P(>48) ~ 1e-12)
#define GRES    14     // hash grid resolution; 1/14 = 0.0714 > R = 0.07
#define GCELLS  (GRES * GRES * GRES)   // 2744
#define CPAD    72     // sA bf16 row stride: 144 B -> b128-aligned
#define NSCAT   40     // scatter blocks in k2
#define WT_ELEMS (NCELLS * COUT * CIN) // 55296

typedef __attribute__((ext_vector_type(8))) short         bf16x8_t;
typedef __attribute__((ext_vector_type(4))) float         f32x4_t;

__device__ __forceinline__ void cell_coords(float x, float y, float z,
                                            int& cx, int& cy, int& cz) {
    cx = (int)(x * (float)GRES); if (cx > GRES - 1) cx = GRES - 1; if (cx < 0) cx = 0;
    cy = (int)(y * (float)GRES); if (cy > GRES - 1) cy = GRES - 1; if (cy < 0) cy = 0;
    cz = (int)(z * (float)GRES); if (cz > GRES - 1) cz = GRES - 1; if (cz < 0) cz = 0;
}

// fp32 -> bf16 round-to-nearest-even, raw bits (finite inputs)
__device__ __forceinline__ unsigned int f2bf_u(float x) {
    unsigned int u = __float_as_uint(x);
    return (u + 0x7FFFu + ((u >> 16) & 1u)) >> 16;
}

// ---- build k1 (1 block x 1024): LDS histogram (zeroed in LDS -> no memset
// ---- dispatch) + shfl-based scan (3 barriers); writes offsets[] and cursor[].
__global__ __launch_bounds__(1024) void k1_hist_scan(
    const float* __restrict__ pts,
    int* __restrict__ offsets,    // GCELLS+1
    int* __restrict__ cursor)     // GCELLS (= offsets copy for scatter atomics)
{
    __shared__ int s_hist[GCELLS];
    __shared__ int s_wsum[16];
    const int t = threadIdx.x;
    const int lane = t & 63;
    const int wv   = t >> 6;

    for (int i = t; i < GCELLS; i += 1024) s_hist[i] = 0;
    __syncthreads();
    for (int i = t; i < N_PTS; i += 1024) {
        int cx, cy, cz;
        cell_coords(pts[3 * i], pts[3 * i + 1], pts[3 * i + 2], cx, cy, cz);
        atomicAdd(&s_hist[(cx * GRES + cy) * GRES + cz], 1);
    }
    __syncthreads();

    // thread owns 3 cells; wave-level shfl scan + tiny cross-wave scan
    const int c0 = t * 3;
    int v0 = (c0 + 0 < GCELLS) ? s_hist[c0 + 0] : 0;
    int v1 = (c0 + 1 < GCELLS) ? s_hist[c0 + 1] : 0;
    int v2 = (c0 + 2 < GCELLS) ? s_hist[c0 + 2] : 0;
    const int local = v0 + v1 + v2;
    int inc = local;
    #pragma unroll
    for (int d = 1; d < 64; d <<= 1) {
        int up = __shfl_up(inc, d);
        if (lane >= d) inc += up;
    }
    if (lane == 63) s_wsum[wv] = inc;
    __syncthreads();
    if (t == 0) {
        int run = 0;
        #pragma unroll
        for (int i = 0; i < 16; ++i) { int tmp = s_wsum[i]; s_wsum[i] = run; run += tmp; }
    }
    __syncthreads();
    int base = s_wsum[wv] + (inc - local);   // exclusive prefix for this thread
    if (c0 + 0 < GCELLS) { offsets[c0 + 0] = base; cursor[c0 + 0] = base; base += v0; }
    if (c0 + 1 < GCELLS) { offsets[c0 + 1] = base; cursor[c0 + 1] = base; base += v1; }
    if (c0 + 2 < GCELLS) { offsets[c0 + 2] = base; cursor[c0 + 2] = base; base += v2; }
    if (t == 0) offsets[GCELLS] = N_PTS;
}

// ---- build k2 (67 blocks x 256): blocks 0..39 scatter stripes via global
// ---- cursor atomics; blocks 40..66 transpose W[cell] -> bf16 Wt.
__global__ __launch_bounds__(256) void k2_scatter_wt(
    const float* __restrict__ pts,
    const float* __restrict__ W,
    int*   __restrict__ cursor,
    int*   __restrict__ sorted,           // N_PTS
    float* __restrict__ pts_s,            // 3*N_PTS cell-sorted copies
    unsigned short* __restrict__ Wt)      // [cell][o][f] bf16
{
    const int b = blockIdx.x;
    const int t = threadIdx.x;

    if (b < NSCAT) {
        const int per = N_PTS / NSCAT;    // 250
        const int lo = b * per;
        const int hi = lo + per;
        for (int i = lo + t; i < hi; i += 256) {
            float x = pts[3 * i + 0], y = pts[3 * i + 1], z = pts[3 * i + 2];
            int cx, cy, cz;
            cell_coords(x, y, z, cx, cy, cz);
            int cell = (cx * GRES + cy) * GRES + cz;
            int pos = atomicAdd(&cursor[cell], 1);
            sorted[pos] = i;
            pts_s[3 * pos + 0] = x;   // bitwise copies -> d2 stays byte-identical
            pts_s[3 * pos + 1] = y;
            pts_s[3 * pos + 2] = z;
        }
    } else {
        __shared__ float tile[CIN * 33];
        const int cell = b - NSCAT;
        for (int idx = t; idx < CIN * COUT; idx += 256) {
            int f = idx >> 5, o = idx & 31;
            tile[f * 33 + o] = W[cell * (CIN * COUT) + idx];    // coalesced read
        }
        __syncthreads();
        for (int idx = t; idx < CIN * COUT; idx += 256) {
            int o = idx >> 6, f = idx & 63;
            Wt[cell * (CIN * COUT) + idx] = (unsigned short)f2bf_u(tile[f * 33 + o]);
        }
    }
}

// ---- main fused kernel ----
__global__ __launch_bounds__(256) void cconv_grid_mfma_kernel(
    const float* __restrict__ feats,
    const unsigned short* __restrict__ Wt,   // [27][32][64] bf16
    const float* __restrict__ bias,
    const int*   __restrict__ offsets,
    const int*   __restrict__ sorted,
    const float* __restrict__ pts_s,         // cell-sorted point copies
    float* __restrict__ out)
{
    const int tid  = threadIdx.x;
    const int lane = tid & 63;
    const int wave = tid >> 6;

    // ~21.3 KB -> 7 blocks/CU
    __shared__ __align__(16) unsigned short sAb[QB][NCELLS + 1][CPAD];  // 16128 B (28 rows: row 27 = zero pad)
    __shared__ __align__(16) float s_pool[QB][4][MAXC];                 // 3072 B {d2,x,y,z}; sC overlay later
    __shared__ int   s_idx[QB][MAXC];                                   // gidx (position in sorted/pts_s)
    __shared__ int   s_org[QB][MAXC];                                   // original indices (tie-break, feats)
    __shared__ int   s_sel[QB][KCAP];
    __shared__ int   s_cnt[QB];
    __shared__ int   s_qi[QB];
    __shared__ int   s_nn[QB];

    if (lane == 0) s_cnt[wave] = 0;

    const int q_flat = blockIdx.x * QB + wave;
    const int qi = sorted[q_flat];
    const float qx = pts_s[3 * q_flat + 0];   // == points[qi], bitwise
    const float qy = pts_s[3 * q_flat + 1];
    const float qz = pts_s[3 * q_flat + 2];
    const float sqn = qx * qx + qy * qy + qz * qz;
    const float r2 = RADIUSF * RADIUSF;

    int cx, cy, cz;
    cell_coords(qx, qy, qz, cx, cy, cz);

    // ---- Phase 1: flattened candidate scan over up to 9 z-row segments ----
    int zlo = cz - 1; if (zlo < 0) zlo = 0;
    int zhi = cz + 1; if (zhi > GRES - 1) zhi = GRES - 1;
    int ss[9], sl[9];
    #pragma unroll
    for (int dxi = 0; dxi < 3; ++dxi) {
        #pragma unroll
        for (int dyi = 0; dyi < 3; ++dyi) {
            const int ii = dxi * 3 + dyi;
            int cxx = cx + dxi - 1, cyy = cy + dyi - 1;
            bool ok = (cxx >= 0) && (cxx <= GRES - 1) && (cyy >= 0) && (cyy <= GRES - 1);
            int row = ((ok ? cxx : 0) * GRES + (ok ? cyy : 0)) * GRES;
            int s = offsets[row + zlo];
            int e = offsets[row + zhi + 1];
            ss[ii] = s;
            sl[ii] = ok ? (e - s) : 0;
        }
    }
    int cum[10];
    cum[0] = 0;
    #pragma unroll
    for (int ii = 0; ii < 9; ++ii) cum[ii + 1] = cum[ii] + sl[ii];
    const int T = cum[9];

    for (int t = lane; t < T; t += 64) {
        int gidx = 0;
        #pragma unroll
        for (int ii = 0; ii < 9; ++ii) {
            bool in = (t >= cum[ii]) && (t < cum[ii + 1]);
            int cand = ss[ii] + (t - cum[ii]);
            gidx = in ? cand : gidx;
        }
        float x = pts_s[3 * gidx + 0];
        float y = pts_s[3 * gidx + 1];
        float z = pts_s[3 * gidx + 2];
        float sqj = x * x + y * y + z * z;
        float dot = qx * x + qy * y + qz * z;
        float d2 = (sqn + sqj) - 2.0f * dot;   // byte-identical to ref form
        if (d2 <= r2) {
            int pos = atomicAdd(&s_cnt[wave], 1);
            if (pos < MAXC) {
                s_pool[wave][0][pos] = d2;
                s_pool[wave][1][pos] = x;
                s_pool[wave][2][pos] = y;
                s_pool[wave][3][pos] = z;
                s_idx[wave][pos] = gidx;       // no dependent sorted[] load here
            }
        }
    }

    int M = s_cnt[wave]; if (M > MAXC) M = MAXC;
    const int cnt = (M > KCAP) ? KCAP : M;
    const bool over = (M > KCAP);

    // batch-resolve original indices (lane-parallel, off the gather critical path)
    if (lane < M) s_org[wave][lane] = sorted[s_idx[wave][lane]];

    if (over) {   // exact top-32; tie-break matches lax.top_k (d2, then original index)
        if (lane < M) {
            float dc = s_pool[wave][0][lane];
            int   ic = s_org[wave][lane];
            int rank = 0;
            for (int m = 0; m < M; ++m) {
                float dm = s_pool[wave][0][m];
                int   im = s_org[wave][m];
                rank += (dm < dc || (dm == dc && im < ic)) ? 1 : 0;
            }
            if (rank < KCAP) s_sel[wave][rank] = lane;   // store SLOT
        }
    }
    if (lane == 0) { s_qi[wave] = qi; s_nn[wave] = cnt; }

    // ---- Phase 2a: per-neighbor trilinear weights computed ONCE, in parallel ----
    float* w9w = (float*)&sAb[wave][0][0];   // 1536 B overlay in dead sAb region
    if (lane < cnt) {
        int slot = over ? s_sel[wave][lane] : lane;
        float x = s_pool[wave][1][slot];
        float y = s_pool[wave][2][slot];
        float z = s_pool[wave][3][slot];
        int   j = s_org[wave][slot];
        float rx = (x - qx) / RADIUSF;
        float ry = (y - qy) / RADIUSF;
        float rz = (z - qz) / RADIUSF;
        float l2 = sqrtf(rx * rx + ry * ry + rz * rz);
        float ax = fabsf(rx), ay = fabsf(ry), az = fabsf(rz);
        float linf = fmaxf(fmaxf(ax, ay), az);
        float s = (linf > 0.0f) ? (l2 / fmaxf(linf, 1e-12f)) : 0.0f;
        float tx = rx * s, ty = ry * s, tz = rz * s;
        float cxf = (tx + 1.0f) * 0.5f * 2.0f;
        float cyf = (ty + 1.0f) * 0.5f * 2.0f;
        float czf = (tz + 1.0f) * 0.5f * 2.0f;
        float c0x = fminf(fmaxf(floorf(cxf), 0.0f), 1.0f);
        float c0y = fminf(fmaxf(floorf(cyf), 0.0f), 1.0f);
        float c0z = fminf(fmaxf(floorf(czf), 0.0f), 1.0f);
        float fx = cxf - c0x;
        float fy = cyf - c0y;
        float fz = czf - c0z;
        int i0 = (int)c0x, i1 = (int)c0y, i2 = (int)c0z;
        float gx0 = 1.0f - fx, gx1 = fx;
        float gy0 = 1.0f - fy, gy1 = fy;
        float gz0 = 1.0f - fz, gz1 = fz;
        float* wp = w9w + lane * 12;
        wp[0] = i0 ? 0.0f : gx0;  wp[1] = i0 ? gx0 : gx1;  wp[2] = i0 ? gx1 : 0.0f;
        wp[3] = i1 ? 0.0f : gy0;  wp[4] = i1 ? gy0 : gy1;  wp[5] = i1 ? gy1 : 0.0f;
        wp[6] = i2 ? 0.0f : gz0;  wp[7] = i2 ? gz0 : gz1;  wp[8] = i2 ? gz1 : 0.0f;
        wp[9] = __int_as_float(j * CIN);
    }

    // ---- Phase 2b: register-accumulated scatter (lane = feature), depth-2 prefetch ----
    float a[NCELLS];
    #pragma unroll
    for (int c = 0; c < NCELLS; ++c) a[c] = 0.0f;

    if (cnt > 0) {
        float fvA = feats[__float_as_int(w9w[9]) + lane];
        float fvB = 0.0f;
        if (cnt > 1) fvB = feats[__float_as_int(w9w[12 + 9]) + lane];
        for (int k = 0; k < cnt; ++k) {
            const float* wp = w9w + k * 12;        // broadcast LDS reads
            float wxv[3] = {wp[0], wp[1], wp[2]};
            float wyv[3] = {wp[3], wp[4], wp[5]};
            float wz0 = wp[6], wz1 = wp[7], wz2 = wp[8];
            float fv_cur = fvA;
            fvA = fvB;
            if (k + 2 < cnt) fvB = feats[__float_as_int(w9w[(k + 2) * 12 + 9]) + lane];
            float pzv[3] = {wz0 * fv_cur, wz1 * fv_cur, wz2 * fv_cur};
            #pragma unroll
            for (int ci = 0; ci < 3; ++ci) {
                #pragma unroll
                for (int cj = 0; cj < 3; ++cj) {
                    float wxy = wxv[ci] * wyv[cj];
                    #pragma unroll
                    for (int ck = 0; ck < 3; ++ck) {
                        a[ci * 9 + cj * 3 + ck] = fmaf(wxy, pzv[ck], a[ci * 9 + cj * 3 + ck]);
                    }
                }
            }
        }
    }
    // store bf16 A (overwrites w9w region - dead now); zero the pad row 27
    #pragma unroll
    for (int c = 0; c < NCELLS; ++c) sAb[wave][c][lane] = (unsigned short)f2bf_u(a[c]);
    sAb[wave][NCELLS][lane] = 0;
    __syncthreads();   // all waves' sAb / s_qi / s_nn now visible; s_pool now dead

    // ---- Phase 3: MFMA contraction, compile-time 14-trip (56 padded K-steps) ----
    float (*sC)[QB][COUT] = (float (*)[QB][COUT])&s_pool[0][0][0];   // overlay
    f32x4_t acc0 = {0.f, 0.f, 0.f, 0.f};
    f32x4_t acc1 = {0.f, 0.f, 0.f, 0.f};
    const int r  = lane & 15;
    const int kg = lane >> 4;
    #pragma unroll
    for (int it = 0; it < 14; ++it) {
        const int s5 = wave + it * 4;          // 0..55, disjoint across waves
        const int c  = s5 >> 1;                // 0..27 (27 = zero pad row)
        const int f0 = (s5 & 1) << 5;
        const int cw = (c < NCELLS) ? c : 0;   // any valid Wt addr; af==0 there
        bf16x8_t af = {};
        if (r < QB) af = *(const bf16x8_t*)&sAb[r][c][f0 + kg * 8];   // one ds_read_b128
        const unsigned short* wp0 = Wt + ((cw * COUT + r     ) * CIN + f0 + kg * 8);
        const unsigned short* wp1 = Wt + ((cw * COUT + 16 + r) * CIN + f0 + kg * 8);
        bf16x8_t bf0 = *(const bf16x8_t*)wp0;
        bf16x8_t bf1 = *(const bf16x8_t*)wp1;
        acc0 = __builtin_amdgcn_mfma_f32_16x16x32_bf16(af, bf0, acc0, 0, 0, 0);
        acc1 = __builtin_amdgcn_mfma_f32_16x16x32_bf16(af, bf1, acc1, 0, 0, 0);
    }
    if (lane < 16) {
        #pragma unroll
        for (int j = 0; j < QB; ++j) {
            sC[wave][j][lane]      = acc0[j];
            sC[wave][j][16 + lane] = acc1[j];
        }
    }
    __syncthreads();

    if (tid < QB * COUT) {
        int q = tid >> 5, o = tid & 31;
        float v = sC[0][q][o] + sC[1][q][o] + sC[2][q][o] + sC[3][q][o];
        float nn = (float)s_nn[q];
        out[s_qi[q] * COUT + o] = v / fmaxf(nn, 1.0f) + bias[o];
    }
}

// ---- fallback (validated Round-3 kernel) if workspace is too small ----
__global__ __launch_bounds__(64) void cconv_fused_kernel(
    const float* __restrict__ feats,
    const float* __restrict__ points,
    const float* __restrict__ W,
    const float* __restrict__ bias,
    float* __restrict__ out)
{
    const int n    = blockIdx.x;
    const int lane = threadIdx.x;

    __shared__ float sA[NCELLS][CIN];
    __shared__ float s_d2[128];
    __shared__ int   s_idx[128];
    __shared__ int   s_rank[128];
    __shared__ int   s_sel[KCAP];
    __shared__ int   s_cnt;

    if (lane == 0) s_cnt = 0;
    for (int c = lane; c < NCELLS * CIN; c += 64) ((float*)sA)[c] = 0.0f;
    __syncthreads();

    const float qx = points[3 * n + 0];
    const float qy = points[3 * n + 1];
    const float qz = points[3 * n + 2];
    const float sqn = qx * qx + qy * qy + qz * qz;
    const float r2 = RADIUSF * RADIUSF;

    for (int j = lane; j < N_PTS; j += 64) {
        float x = points[3 * j + 0];
        float y = points[3 * j + 1];
        float z = points[3 * j + 2];
        float sqj = x * x + y * y + z * z;
        float dot = qx * x + qy * y + qz * z;
        float d2 = (sqn + sqj) - 2.0f * dot;
        if (d2 <= r2) {
            int pos = atomicAdd(&s_cnt, 1);
            if (pos < 128) { s_d2[pos] = d2; s_idx[pos] = j; }
        }
    }
    __syncthreads();

    int M = s_cnt; if (M > 128) M = 128;
    int cnt;
    if (M > KCAP) {
        for (int c = lane; c < M; c += 64) {
            float dc = s_d2[c]; int ic = s_idx[c]; int rank = 0;
            for (int m = 0; m < M; ++m) {
                float dm = s_d2[m]; int im = s_idx[m];
                rank += (dm < dc || (dm == dc && im < ic)) ? 1 : 0;
            }
            s_rank[c] = rank;
        }
        __syncthreads();
        for (int c = lane; c < M; c += 64) {
            int r = s_rank[c];
            if (r < KCAP) s_sel[r] = s_idx[c];
        }
        __syncthreads();
        cnt = KCAP;
    } else cnt = M;
    const int* nbr = (M > KCAP) ? s_sel : s_idx;

    for (int k = 0; k < cnt; ++k) {
        int j = nbr[k];
        float x = points[3 * j + 0];
        float y = points[3 * j + 1];
        float z = points[3 * j + 2];
        float rx = (x - qx) / RADIUSF;
        float ry = (y - qy) / RADIUSF;
        float rz = (z - qz) / RADIUSF;
        float l2 = sqrtf(rx * rx + ry * ry + rz * rz);
        float ax = fabsf(rx), ay = fabsf(ry), az = fabsf(rz);
        float linf = fmaxf(fmaxf(ax, ay), az);
        float s = (linf > 0.0f) ? (l2 / fmaxf(linf, 1e-12f)) : 0.0f;
        float tx = rx * s, ty = ry * s, tz = rz * s;
        float cxf = (tx + 1.0f) * 0.5f * 2.0f;
        float cyf = (ty + 1.0f) * 0.5f * 2.0f;
        float czf = (tz + 1.0f) * 0.5f * 2.0f;
        float c0x = fminf(fmaxf(floorf(cxf), 0.0f), 1.0f);
        float c0y = fminf(fmaxf(floorf(cyf), 0.0f), 1.0f);
        float c0z = fminf(fmaxf(floorf(czf), 0.0f), 1.0f);
        float fx = cxf - c0x, fy = cyf - c0y, fz = czf - c0z;
        int i0 = (int)c0x, i1 = (int)c0y, i2 = (int)c0z;
        int base = i0 * 9 + i1 * 3 + i2;
        float gx0 = 1.0f - fx, gx1 = fx;
        float gy0 = 1.0f - fy, gy1 = fy;
        float gz0 = 1.0f - fz, gz1 = fz;
        float featv = feats[j * CIN + lane];
        sA[base + 0 ][lane] += (gx0 * gy0) * gz0 * featv;
        sA[base + 1 ][lane] += (gx0 * gy0) * gz1 * featv;
        sA[base + 3 ][lane] += (gx0 * gy1) * gz0 * featv;
        sA[base + 4 ][lane] += (gx0 * gy1) * gz1 * featv;
        sA[base + 9 ][lane] += (gx1 * gy0) * gz0 * featv;
        sA[base + 10][lane] += (gx1 * gy0) * gz1 * featv;
        sA[base + 12][lane] += (gx1 * gy1) * gz0 * featv;
        sA[base + 13][lane] += (gx1 * gy1) * gz1 * featv;
    }
    __syncthreads();

    const int o    = lane & 31;
    const int half = lane >> 5;
    const int c_begin = half ? 14 : 0;
    const int c_end   = half ? 27 : 14;
    float acc = 0.0f;
    for (int cell = c_begin; cell < c_end; ++cell) {
        const float* __restrict__ Wrow = W + (cell * CIN) * COUT + o;
        #pragma unroll 8
        for (int f = 0; f < CIN; ++f) acc += sA[cell][f] * Wrow[f * COUT];
    }
    acc += __shfl_xor(acc, 32);
    if (lane < COUT) {
        float nn = (float)cnt;
        out[n * COUT + lane] = acc / fmaxf(nn, 1.0f) + bias[lane];
    }
}

extern "C" void kernel_launch(void* const* d_in, const int* in_sizes, int n_in,
                              void* d_out, int out_size, void* d_ws, size_t ws_size,
                              hipStream_t stream) {
    const float* feats  = (const float*)d_in[0];
    const float* points = (const float*)d_in[1];
    const float* W      = (const float*)d_in[2];
    const float* bias   = (const float*)d_in[3];
    float* out = (float*)d_out;

    // ws layout: Wt bf16 | offsets | cursor | sorted | pts_s
    const size_t wt_bytes = (size_t)WT_ELEMS * sizeof(unsigned short);   // 110592
    const size_t need     = wt_bytes
                          + (size_t)(GCELLS + 1 + GCELLS + N_PTS) * sizeof(int)
                          + (size_t)3 * N_PTS * sizeof(float);

    if (ws_size >= need) {
        unsigned short* Wt = (unsigned short*)d_ws;
        int* offsets = (int*)((char*)d_ws + wt_bytes);   // GCELLS+1
        int* cursor  = offsets + GCELLS + 1;             // GCELLS
        int* sorted  = cursor + GCELLS;                  // N_PTS
        float* pts_s = (float*)(sorted + N_PTS);         // 3*N_PTS

        k1_hist_scan<<<1, 1024, 0, stream>>>(points, offsets, cursor);
        k2_scatter_wt<<<NSCAT + NCELLS, 256, 0, stream>>>(points, W, cursor, sorted, pts_s, Wt);
        cconv_grid_mfma_kernel<<<N_PTS / QB, QB * 64, 0, stream>>>(
            feats, Wt, bias, offsets, sorted, pts_s, out);
    } else {
        cconv_fused_kernel<<<N_PTS, 64, 0, stream>>>(feats, points, W, bias, out);
    }
}

// Round 12
// 105.666 us; speedup vs baseline: 1.6703x; 1.0915x over previous
//
#include <hip/hip_runtime.h>
#include <math.h>

#define N_PTS   10000
#define CIN     64
#define COUT    32
#define KCAP    32
#define RADIUSF 0.07f
#define NCELLS  27
#define QB      8      // queries per block (8 waves; wave w owns query w; MFMA rows 0-7)
#define MAXC    48     // per-query in-radius cap (Poisson(14.4): P(>48) ~ 1e-12)
#define GRES    14     // hash grid resolution; 1/14 = 0.0714 > R = 0.07
#define GCELLS  (GRES * GRES * GRES)   // 2744
#define CPAD    72     // sAb bf16 row stride: 144 B -> b128-aligned
#define NSCAT   40     // scatter blocks in k2
#define WT_ELEMS (NCELLS * COUT * CIN) // 55296

typedef __attribute__((ext_vector_type(8))) short         bf16x8_t;
typedef __attribute__((ext_vector_type(4))) float         f32x4_t;

__device__ __forceinline__ void cell_coords(float x, float y, float z,
                                            int& cx, int& cy, int& cz) {
    cx = (int)(x * (float)GRES); if (cx > GRES - 1) cx = GRES - 1; if (cx < 0) cx = 0;
    cy = (int)(y * (float)GRES); if (cy > GRES - 1) cy = GRES - 1; if (cy < 0) cy = 0;
    cz = (int)(z * (float)GRES); if (cz > GRES - 1) cz = GRES - 1; if (cz < 0) cz = 0;
}

// fp32 -> bf16 round-to-nearest-even, raw bits (finite inputs)
__device__ __forceinline__ unsigned int f2bf_u(float x) {
    unsigned int u = __float_as_uint(x);
    return (u + 0x7FFFu + ((u >> 16) & 1u)) >> 16;
}

// ---- build k1 (28 blocks x 1024): block 0 = LDS histogram + shfl scan ->
// ---- offsets/cursor; blocks 1..27 = W[cell] f32->bf16 transpose (independent).
__global__ __launch_bounds__(1024) void k1_hist_scan_wt(
    const float* __restrict__ pts,
    const float* __restrict__ W,
    int* __restrict__ offsets,    // GCELLS+1
    int* __restrict__ cursor,     // GCELLS
    unsigned short* __restrict__ Wt)
{
    const int t = threadIdx.x;
    const int b = blockIdx.x;

    if (b >= 1) {   // W transpose for cell b-1
        __shared__ float tile[CIN * 33];
        const int cell = b - 1;
        for (int idx = t; idx < CIN * COUT; idx += 1024) {
            int f = idx >> 5, o = idx & 31;
            tile[f * 33 + o] = W[cell * (CIN * COUT) + idx];    // coalesced read
        }
        __syncthreads();
        for (int idx = t; idx < CIN * COUT; idx += 1024) {
            int o = idx >> 6, f = idx & 63;
            Wt[cell * (CIN * COUT) + idx] = (unsigned short)f2bf_u(tile[f * 33 + o]);
        }
        return;
    }

    __shared__ int s_hist[GCELLS];
    __shared__ int s_wsum[16];
    const int lane = t & 63;
    const int wv   = t >> 6;

    for (int i = t; i < GCELLS; i += 1024) s_hist[i] = 0;
    __syncthreads();
    for (int i = t; i < N_PTS; i += 1024) {
        int cx, cy, cz;
        cell_coords(pts[3 * i], pts[3 * i + 1], pts[3 * i + 2], cx, cy, cz);
        atomicAdd(&s_hist[(cx * GRES + cy) * GRES + cz], 1);
    }
    __syncthreads();

    const int c0 = t * 3;
    int v0 = (c0 + 0 < GCELLS) ? s_hist[c0 + 0] : 0;
    int v1 = (c0 + 1 < GCELLS) ? s_hist[c0 + 1] : 0;
    int v2 = (c0 + 2 < GCELLS) ? s_hist[c0 + 2] : 0;
    const int local = v0 + v1 + v2;
    int inc = local;
    #pragma unroll
    for (int d = 1; d < 64; d <<= 1) {
        int up = __shfl_up(inc, d);
        if (lane >= d) inc += up;
    }
    if (lane == 63) s_wsum[wv] = inc;
    __syncthreads();
    if (t == 0) {
        int run = 0;
        #pragma unroll
        for (int i = 0; i < 16; ++i) { int tmp = s_wsum[i]; s_wsum[i] = run; run += tmp; }
    }
    __syncthreads();
    int base = s_wsum[wv] + (inc - local);
    if (c0 + 0 < GCELLS) { offsets[c0 + 0] = base; cursor[c0 + 0] = base; base += v0; }
    if (c0 + 1 < GCELLS) { offsets[c0 + 1] = base; cursor[c0 + 1] = base; base += v1; }
    if (c0 + 2 < GCELLS) { offsets[c0 + 2] = base; cursor[c0 + 2] = base; base += v2; }
    if (t == 0) offsets[GCELLS] = N_PTS;
}

// ---- build k2 (40 blocks x 256): scatter indices + cell-sorted point copies ----
__global__ __launch_bounds__(256) void k2_scatter(
    const float* __restrict__ pts,
    int*   __restrict__ cursor,
    int*   __restrict__ sorted,
    float* __restrict__ pts_s)
{
    const int b = blockIdx.x;
    const int t = threadIdx.x;
    const int per = N_PTS / NSCAT;    // 250
    const int lo = b * per;
    const int hi = lo + per;
    for (int i = lo + t; i < hi; i += 256) {
        float x = pts[3 * i + 0], y = pts[3 * i + 1], z = pts[3 * i + 2];
        int cx, cy, cz;
        cell_coords(x, y, z, cx, cy, cz);
        int cell = (cx * GRES + cy) * GRES + cz;
        int pos = atomicAdd(&cursor[cell], 1);
        sorted[pos] = i;
        pts_s[3 * pos + 0] = x;   // bitwise copies -> d2 stays byte-identical
        pts_s[3 * pos + 1] = y;
        pts_s[3 * pos + 2] = z;
    }
}

// ---- main fused kernel: 8 queries/block, MFMA rows 0-7 ----
__global__ __launch_bounds__(512) void cconv_grid_mfma_kernel(
    const float* __restrict__ feats,
    const unsigned short* __restrict__ Wt,   // [27][32][64] bf16
    const float* __restrict__ bias,
    const int*   __restrict__ offsets,
    const int*   __restrict__ sorted,
    const float* __restrict__ pts_s,
    float* __restrict__ out)
{
    const int tid  = threadIdx.x;
    const int lane = tid & 63;
    const int wave = tid >> 6;

    // ~44.6 KB -> 3 blocks/CU
    __shared__ __align__(16) unsigned short sAb[QB][NCELLS + 1][CPAD];  // 32256 B (row 27 = zero pad)
    __shared__ __align__(16) float s_scratch[2048];                     // 8192 B: pool[8][4][48] then sC[8][8][32]
    __shared__ int   s_idx[QB][MAXC];
    __shared__ int   s_org[QB][MAXC];
    __shared__ int   s_sel[QB][KCAP];
    __shared__ int   s_cnt[QB];
    __shared__ int   s_qi[QB];
    __shared__ int   s_nn[QB];

    float (*s_pool)[4][MAXC] = (float (*)[4][MAXC])s_scratch;   // phase 1/2 view

    if (lane == 0) s_cnt[wave] = 0;

    const int q_flat = blockIdx.x * QB + wave;
    const int qi = sorted[q_flat];
    const float qx = pts_s[3 * q_flat + 0];   // == points[qi], bitwise
    const float qy = pts_s[3 * q_flat + 1];
    const float qz = pts_s[3 * q_flat + 2];
    const float sqn = qx * qx + qy * qy + qz * qz;
    const float r2 = RADIUSF * RADIUSF;

    int cx, cy, cz;
    cell_coords(qx, qy, qz, cx, cy, cz);

    // ---- Phase 1: flattened candidate scan over up to 9 z-row segments ----
    int zlo = cz - 1; if (zlo < 0) zlo = 0;
    int zhi = cz + 1; if (zhi > GRES - 1) zhi = GRES - 1;
    int ss[9], sl[9];
    #pragma unroll
    for (int dxi = 0; dxi < 3; ++dxi) {
        #pragma unroll
        for (int dyi = 0; dyi < 3; ++dyi) {
            const int ii = dxi * 3 + dyi;
            int cxx = cx + dxi - 1, cyy = cy + dyi - 1;
            bool ok = (cxx >= 0) && (cxx <= GRES - 1) && (cyy >= 0) && (cyy <= GRES - 1);
            int row = ((ok ? cxx : 0) * GRES + (ok ? cyy : 0)) * GRES;
            int s = offsets[row + zlo];
            int e = offsets[row + zhi + 1];
            ss[ii] = s;
            sl[ii] = ok ? (e - s) : 0;
        }
    }
    int cum[10];
    cum[0] = 0;
    #pragma unroll
    for (int ii = 0; ii < 9; ++ii) cum[ii + 1] = cum[ii] + sl[ii];
    const int T = cum[9];

    for (int t = lane; t < T; t += 64) {
        int gidx = 0;
        #pragma unroll
        for (int ii = 0; ii < 9; ++ii) {
            bool in = (t >= cum[ii]) && (t < cum[ii + 1]);
            int cand = ss[ii] + (t - cum[ii]);
            gidx = in ? cand : gidx;
        }
        float x = pts_s[3 * gidx + 0];
        float y = pts_s[3 * gidx + 1];
        float z = pts_s[3 * gidx + 2];
        float sqj = x * x + y * y + z * z;
        float dot = qx * x + qy * y + qz * z;
        float d2 = (sqn + sqj) - 2.0f * dot;   // byte-identical to ref form
        if (d2 <= r2) {
            int pos = atomicAdd(&s_cnt[wave], 1);
            if (pos < MAXC) {
                s_pool[wave][0][pos] = d2;
                s_pool[wave][1][pos] = x;
                s_pool[wave][2][pos] = y;
                s_pool[wave][3][pos] = z;
                s_idx[wave][pos] = gidx;
            }
        }
    }

    int M = s_cnt[wave]; if (M > MAXC) M = MAXC;
    const int cnt = (M > KCAP) ? KCAP : M;
    const bool over = (M > KCAP);

    if (lane < M) s_org[wave][lane] = sorted[s_idx[wave][lane]];   // batch resolve

    if (over) {   // exact top-32; tie-break matches lax.top_k (d2, then original index)
        if (lane < M) {
            float dc = s_pool[wave][0][lane];
            int   ic = s_org[wave][lane];
            int rank = 0;
            for (int m = 0; m < M; ++m) {
                float dm = s_pool[wave][0][m];
                int   im = s_org[wave][m];
                rank += (dm < dc || (dm == dc && im < ic)) ? 1 : 0;
            }
            if (rank < KCAP) s_sel[wave][rank] = lane;   // store SLOT
        }
    }
    if (lane == 0) { s_qi[wave] = qi; s_nn[wave] = cnt; }

    // ---- Phase 2a: per-neighbor trilinear weights computed ONCE, in parallel ----
    float* w9w = (float*)&sAb[wave][0][0];   // 1536 B overlay in dead per-wave sAb region
    if (lane < cnt) {
        int slot = over ? s_sel[wave][lane] : lane;
        float x = s_pool[wave][1][slot];
        float y = s_pool[wave][2][slot];
        float z = s_pool[wave][3][slot];
        int   j = s_org[wave][slot];
        float rx = (x - qx) / RADIUSF;
        float ry = (y - qy) / RADIUSF;
        float rz = (z - qz) / RADIUSF;
        float l2 = sqrtf(rx * rx + ry * ry + rz * rz);
        float ax = fabsf(rx), ay = fabsf(ry), az = fabsf(rz);
        float linf = fmaxf(fmaxf(ax, ay), az);
        float s = (linf > 0.0f) ? (l2 / fmaxf(linf, 1e-12f)) : 0.0f;
        float tx = rx * s, ty = ry * s, tz = rz * s;
        float cxf = (tx + 1.0f) * 0.5f * 2.0f;
        float cyf = (ty + 1.0f) * 0.5f * 2.0f;
        float czf = (tz + 1.0f) * 0.5f * 2.0f;
        float c0x = fminf(fmaxf(floorf(cxf), 0.0f), 1.0f);
        float c0y = fminf(fmaxf(floorf(cyf), 0.0f), 1.0f);
        float c0z = fminf(fmaxf(floorf(czf), 0.0f), 1.0f);
        float fx = cxf - c0x;
        float fy = cyf - c0y;
        float fz = czf - c0z;
        int i0 = (int)c0x, i1 = (int)c0y, i2 = (int)c0z;
        float gx0 = 1.0f - fx, gx1 = fx;
        float gy0 = 1.0f - fy, gy1 = fy;
        float gz0 = 1.0f - fz, gz1 = fz;
        float* wp = w9w + lane * 12;
        wp[0] = i0 ? 0.0f : gx0;  wp[1] = i0 ? gx0 : gx1;  wp[2] = i0 ? gx1 : 0.0f;
        wp[3] = i1 ? 0.0f : gy0;  wp[4] = i1 ? gy0 : gy1;  wp[5] = i1 ? gy1 : 0.0f;
        wp[6] = i2 ? 0.0f : gz0;  wp[7] = i2 ? gz0 : gz1;  wp[8] = i2 ? gz1 : 0.0f;
        wp[9] = __int_as_float(j * CIN);
    }

    // ---- Phase 2b: register-accumulated scatter (lane = feature), depth-2 prefetch ----
    float a[NCELLS];
    #pragma unroll
    for (int c = 0; c < NCELLS; ++c) a[c] = 0.0f;

    if (cnt > 0) {
        float fvA = feats[__float_as_int(w9w[9]) + lane];
        float fvB = 0.0f;
        if (cnt > 1) fvB = feats[__float_as_int(w9w[12 + 9]) + lane];
        for (int k = 0; k < cnt; ++k) {
            const float* wp = w9w + k * 12;
            float wxv[3] = {wp[0], wp[1], wp[2]};
            float wyv[3] = {wp[3], wp[4], wp[5]};
            float wz0 = wp[6], wz1 = wp[7], wz2 = wp[8];
            float fv_cur = fvA;
            fvA = fvB;
            if (k + 2 < cnt) fvB = feats[__float_as_int(w9w[(k + 2) * 12 + 9]) + lane];
            float pzv[3] = {wz0 * fv_cur, wz1 * fv_cur, wz2 * fv_cur};
            #pragma unroll
            for (int ci = 0; ci < 3; ++ci) {
                #pragma unroll
                for (int cj = 0; cj < 3; ++cj) {
                    float wxy = wxv[ci] * wyv[cj];
                    #pragma unroll
                    for (int ck = 0; ck < 3; ++ck) {
                        a[ci * 9 + cj * 3 + ck] = fmaf(wxy, pzv[ck], a[ci * 9 + cj * 3 + ck]);
                    }
                }
            }
        }
    }
    #pragma unroll
    for (int c = 0; c < NCELLS; ++c) sAb[wave][c][lane] = (unsigned short)f2bf_u(a[c]);
    sAb[wave][NCELLS][lane] = 0;     // zero pad row
    __syncthreads();   // all waves' sAb / s_qi / s_nn visible; pool dead

    // ---- Phase 3: MFMA contraction, 56 padded K-steps, 7/wave, depth-2 SW pipeline ----
    f32x4_t acc0 = {0.f, 0.f, 0.f, 0.f};
    f32x4_t acc1 = {0.f, 0.f, 0.f, 0.f};
    const int r  = lane & 15;
    const int kg = lane >> 4;

    // step addressing: s5 = wave + it*8 (it 0..6), c = s5>>1, f0 = (s5&1)<<5
    #define STEP_ADDR(it, cvar, fvar, cwvar)                                   \
        const int s5_##it = wave + (it) * 8;                                   \
        const int cvar = s5_##it >> 1;                                         \
        const int fvar = (s5_##it & 1) << 5;                                   \
        const int cwvar = (cvar < NCELLS) ? cvar : 0;

    // preload step 0
    STEP_ADDR(0, c_0, f_0, cw_0)
    bf16x8_t aCur = {}, bCur0, bCur1;
    if (r < QB) aCur = *(const bf16x8_t*)&sAb[r][c_0][f_0 + kg * 8];
    bCur0 = *(const bf16x8_t*)(Wt + ((cw_0 * COUT + r     ) * CIN + f_0 + kg * 8));
    bCur1 = *(const bf16x8_t*)(Wt + ((cw_0 * COUT + 16 + r) * CIN + f_0 + kg * 8));

    #pragma unroll
    for (int it = 0; it < 7; ++it) {
        bf16x8_t aNxt = {}, bNxt0 = {}, bNxt1 = {};
        if (it + 1 < 7) {
            const int s5n = wave + (it + 1) * 8;
            const int cn  = s5n >> 1;
            const int fn  = (s5n & 1) << 5;
            const int cwn = (cn < NCELLS) ? cn : 0;
            if (r < QB) aNxt = *(const bf16x8_t*)&sAb[r][cn][fn + kg * 8];
            bNxt0 = *(const bf16x8_t*)(Wt + ((cwn * COUT + r     ) * CIN + fn + kg * 8));
            bNxt1 = *(const bf16x8_t*)(Wt + ((cwn * COUT + 16 + r) * CIN + fn + kg * 8));
        }
        acc0 = __builtin_amdgcn_mfma_f32_16x16x32_bf16(aCur, bCur0, acc0, 0, 0, 0);
        acc1 = __builtin_amdgcn_mfma_f32_16x16x32_bf16(aCur, bCur1, acc1, 0, 0, 0);
        aCur = aNxt; bCur0 = bNxt0; bCur1 = bNxt1;
    }
    #undef STEP_ADDR

    // partials: lanes 0-31 hold rows 0-7 (row = 4*kg + reg)
    float (*sC)[QB][COUT] = (float (*)[QB][COUT])s_scratch;   // overlay, pool dead
    if (lane < 32) {
        int qrow = (lane >> 4) * 4;
        int o = lane & 15;
        #pragma unroll
        for (int j = 0; j < 4; ++j) {
            sC[wave][qrow + j][o]      = acc0[j];
            sC[wave][qrow + j][16 + o] = acc1[j];
        }
    }
    __syncthreads();

    if (tid < QB * COUT) {
        int q = tid >> 5, o = tid & 31;
        float v = 0.0f;
        #pragma unroll
        for (int w = 0; w < QB; ++w) v += sC[w][q][o];
        float nn = (float)s_nn[q];
        out[s_qi[q] * COUT + o] = v / fmaxf(nn, 1.0f) + bias[o];
    }
}

// ---- fallback (validated Round-3 kernel) if workspace is too small ----
__global__ __launch_bounds__(64) void cconv_fused_kernel(
    const float* __restrict__ feats,
    const float* __restrict__ points,
    const float* __restrict__ W,
    const float* __restrict__ bias,
    float* __restrict__ out)
{
    const int n    = blockIdx.x;
    const int lane = threadIdx.x;

    __shared__ float sA[NCELLS][CIN];
    __shared__ float s_d2[128];
    __shared__ int   s_idx[128];
    __shared__ int   s_rank[128];
    __shared__ int   s_sel[KCAP];
    __shared__ int   s_cnt;

    if (lane == 0) s_cnt = 0;
    for (int c = lane; c < NCELLS * CIN; c += 64) ((float*)sA)[c] = 0.0f;
    __syncthreads();

    const float qx = points[3 * n + 0];
    const float qy = points[3 * n + 1];
    const float qz = points[3 * n + 2];
    const float sqn = qx * qx + qy * qy + qz * qz;
    const float r2 = RADIUSF * RADIUSF;

    for (int j = lane; j < N_PTS; j += 64) {
        float x = points[3 * j + 0];
        float y = points[3 * j + 1];
        float z = points[3 * j + 2];
        float sqj = x * x + y * y + z * z;
        float dot = qx * x + qy * y + qz * z;
        float d2 = (sqn + sqj) - 2.0f * dot;
        if (d2 <= r2) {
            int pos = atomicAdd(&s_cnt, 1);
            if (pos < 128) { s_d2[pos] = d2; s_idx[pos] = j; }
        }
    }
    __syncthreads();

    int M = s_cnt; if (M > 128) M = 128;
    int cnt;
    if (M > KCAP) {
        for (int c = lane; c < M; c += 64) {
            float dc = s_d2[c]; int ic = s_idx[c]; int rank = 0;
            for (int m = 0; m < M; ++m) {
                float dm = s_d2[m]; int im = s_idx[m];
                rank += (dm < dc || (dm == dc && im < ic)) ? 1 : 0;
            }
            s_rank[c] = rank;
        }
        __syncthreads();
        for (int c = lane; c < M; c += 64) {
            int r = s_rank[c];
            if (r < KCAP) s_sel[r] = s_idx[c];
        }
        __syncthreads();
        cnt = KCAP;
    } else cnt = M;
    const int* nbr = (M > KCAP) ? s_sel : s_idx;

    for (int k = 0; k < cnt; ++k) {
        int j = nbr[k];
        float x = points[3 * j + 0];
        float y = points[3 * j + 1];
        float z = points[3 * j + 2];
        float rx = (x - qx) / RADIUSF;
        float ry = (y - qy) / RADIUSF;
        float rz = (z - qz) / RADIUSF;
        float l2 = sqrtf(rx * rx + ry * ry + rz * rz);
        float ax = fabsf(rx), ay = fabsf(ry), az = fabsf(rz);
        float linf = fmaxf(fmaxf(ax, ay), az);
        float s = (linf > 0.0f) ? (l2 / fmaxf(linf, 1e-12f)) : 0.0f;
        float tx = rx * s, ty = ry * s, tz = rz * s;
        float cxf = (tx + 1.0f) * 0.5f * 2.0f;
        float cyf = (ty + 1.0f) * 0.5f * 2.0f;
        float czf = (tz + 1.0f) * 0.5f * 2.0f;
        float c0x = fminf(fmaxf(floorf(cxf), 0.0f), 1.0f);
        float c0y = fminf(fmaxf(floorf(cyf), 0.0f), 1.0f);
        float c0z = fminf(fmaxf(floorf(czf), 0.0f), 1.0f);
        float fx = cxf - c0x, fy = cyf - c0y, fz = czf - c0z;
        int i0 = (int)c0x, i1 = (int)c0y, i2 = (int)c0z;
        int base = i0 * 9 + i1 * 3 + i2;
        float gx0 = 1.0f - fx, gx1 = fx;
        float gy0 = 1.0f - fy, gy1 = fy;
        float gz0 = 1.0f - fz, gz1 = fz;
        float featv = feats[j * CIN + lane];
        sA[base + 0 ][lane] += (gx0 * gy0) * gz0 * featv;
        sA[base + 1 ][lane] += (gx0 * gy0) * gz1 * featv;
        sA[base + 3 ][lane] += (gx0 * gy1) * gz0 * featv;
        sA[base + 4 ][lane] += (gx0 * gy1) * gz1 * featv;
        sA[base + 9 ][lane] += (gx1 * gy0) * gz0 * featv;
        sA[base + 10][lane] += (gx1 * gy0) * gz1 * featv;
        sA[base + 12][lane] += (gx1 * gy1) * gz0 * featv;
        sA[base + 13][lane] += (gx1 * gy1) * gz1 * featv;
    }
    __syncthreads();

    const int o    = lane & 31;
    const int half = lane >> 5;
    const int c_begin = half ? 14 : 0;
    const int c_end   = half ? 27 : 14;
    float acc = 0.0f;
    for (int cell = c_begin; cell < c_end; ++cell) {
        const float* __restrict__ Wrow = W + (cell * CIN) * COUT + o;
        #pragma unroll 8
        for (int f = 0; f < CIN; ++f) acc += sA[cell][f] * Wrow[f * COUT];
    }
    acc += __shfl_xor(acc, 32);
    if (lane < COUT) {
        float nn = (float)cnt;
        out[n * COUT + lane] = acc / fmaxf(nn, 1.0f) + bias[lane];
    }
}

extern "C" void kernel_launch(void* const* d_in, const int* in_sizes, int n_in,
                              void* d_out, int out_size, void* d_ws, size_t ws_size,
                              hipStream_t stream) {
    const float* feats  = (const float*)d_in[0];
    const float* points = (const float*)d_in[1];
    const float* W      = (const float*)d_in[2];
    const float* bias   = (const float*)d_in[3];
    float* out = (float*)d_out;

    // ws layout: Wt bf16 | offsets | cursor | sorted | pts_s
    const size_t wt_bytes = (size_t)WT_ELEMS * sizeof(unsigned short);   // 110592
    const size_t need     = wt_bytes
                          + (size_t)(GCELLS + 1 + GCELLS + N_PTS) * sizeof(int)
                          + (size_t)3 * N_PTS * sizeof(float);

    if (ws_size >= need) {
        unsigned short* Wt = (unsigned short*)d_ws;
        int* offsets = (int*)((char*)d_ws + wt_bytes);   // GCELLS+1
        int* cursor  = offsets + GCELLS + 1;             // GCELLS
        int* sorted  = cursor + GCELLS;                  // N_PTS
        float* pts_s = (float*)(sorted + N_PTS);         // 3*N_PTS

        k1_hist_scan_wt<<<1 + NCELLS, 1024, 0, stream>>>(points, W, offsets, cursor, Wt);
        k2_scatter<<<NSCAT, 256, 0, stream>>>(points, cursor, sorted, pts_s);
        cconv_grid_mfma_kernel<<<N_PTS / QB, QB * 64, 0, stream>>>(
            feats, Wt, bias, offsets, sorted, pts_s, out);
    } else {
        cconv_fused_kernel<<<N_PTS, 64, 0, stream>>>(feats, points, W, bias, out);
    }
}